// Round 16
// baseline (479.643 us; speedup 1.0000x reference)
//
#include <hip/hip_runtime.h>
#include <hip/hip_bf16.h>
#include <math.h>

#define L_SEQ 2048
#define Dm    512
#define DI    1024
#define Nst   16
#define Kc    4
#define Rr    32
#define NL    4
#define CH    64
#define LC    (L_SEQ / CH)   // 32
#define KSX   8              // x_proj split-K
#define NXB   16             // out_proj x-blocks (512/32) = ssp partials per row

typedef __attribute__((ext_vector_type(8))) short bf16x8;
typedef __attribute__((ext_vector_type(4))) float f32x4;

// ---------------- helpers ----------------
__device__ __forceinline__ float act_softplus(float x) {
    return fmaxf(x, 0.f) + log1pf(__expf(-fabsf(x)));
}
__device__ __forceinline__ float act_gelu(float x) {
    float c = 0.7978845608028654f * (x + 0.044715f * x * x * x);
    float t = 1.f - 2.f / (__expf(2.f * c) + 1.f);   // tanh(c)
    return 0.5f * x * (1.f + t);
}
__device__ __forceinline__ float silu_(float x) {
    return x / (1.f + __expf(-x));
}
__device__ __forceinline__ ushort f2bf(float f) {
    union { float f; unsigned u; } c; c.f = f;
    unsigned r = c.u + 0x7fffu + ((c.u >> 16) & 1u);
    return (ushort)(r >> 16);
}
__device__ __forceinline__ float bf2f(ushort u) {
    union { unsigned u; float f; } c; c.u = ((unsigned)u) << 16;
    return c.f;
}
__device__ __forceinline__ float wave_sum(float v) {
    #pragma unroll
    for (int off = 32; off; off >>= 1) v += __shfl_xor(v, off);
    return v;
}

// ---------------- setup: weight casts + LN1 -> res + ssp seed for layer 0 ----------------
__global__ __launch_bounds__(256) void setup_kernel(
    const float* __restrict__ s0, ushort* __restrict__ d0, int n0,
    const float* __restrict__ s1, ushort* __restrict__ d1, int n1,
    const float* __restrict__ s2, ushort* __restrict__ d2, int n2,
    const float* __restrict__ s3, ushort* __restrict__ d3, int n3,
    const float* __restrict__ s4, ushort* __restrict__ d4, int n4_,
    const float* __restrict__ s5, ushort* __restrict__ d5, int n5,
    const float* __restrict__ x, const float* __restrict__ w,
    const float* __restrict__ b,
    float* __restrict__ res, float* __restrict__ ssp)
{
    if (blockIdx.x < 512) {
        int lane = threadIdx.x & 63, wv = threadIdx.x >> 6;
        int row = blockIdx.x * 4 + wv;
        size_t base = (size_t)row * Dm + lane * 8;
        float v[8];
        *(float4*)(v)     = *(const float4*)(x + base);
        *(float4*)(v + 4) = *(const float4*)(x + base + 4);
        float s = 0.f, ss = 0.f;
        #pragma unroll
        for (int q = 0; q < 8; ++q) { s += v[q]; ss += v[q] * v[q]; }
        s = wave_sum(s); ss = wave_sum(ss);
        float mu = s * (1.f / Dm);
        float rs = rsqrtf(ss * (1.f / Dm) - mu * mu + 1e-5f);
        float wv8[8], bv8[8];
        *(float4*)(wv8)     = *(const float4*)(w + lane * 8);
        *(float4*)(wv8 + 4) = *(const float4*)(w + lane * 8 + 4);
        *(float4*)(bv8)     = *(const float4*)(b + lane * 8);
        *(float4*)(bv8 + 4) = *(const float4*)(b + lane * 8 + 4);
        float o[8], ss2 = 0.f;
        #pragma unroll
        for (int q = 0; q < 8; ++q) {
            o[q] = (v[q] - mu) * rs * wv8[q] + bv8[q];
            ss2 += o[q] * o[q];
        }
        *(float4*)(res + base)     = *(float4*)(o);
        *(float4*)(res + base + 4) = *(float4*)(o + 4);
        ss2 = wave_sum(ss2);
        if (lane < NXB)
            ssp[(size_t)lane * L_SEQ + row] = (lane == 0) ? ss2 : 0.f;
        return;
    }
    int i = (blockIdx.x - 512) * 256 + threadIdx.x;
    const float* s; ushort* d;
    if (i < n0) { s = s0; d = d0; }
    else { i -= n0; if (i < n1) { s = s1; d = d1; }
    else { i -= n1; if (i < n2) { s = s2; d = d2; }
    else { i -= n2; if (i < n3) { s = s3; d = d3; }
    else { i -= n3; if (i < n4_) { s = s4; d = d4; }
    else { i -= n4_; if (i < n5) { s = s5; d = d5; } else return; } } } } }
    float4 v = ((const float4*)s)[i];
    ushort4 o;
    o.x = f2bf(v.x); o.y = f2bf(v.y); o.z = f2bf(v.z); o.w = f2bf(v.w);
    ((ushort4*)d)[i] = o;
}

// ---------------- fused: hout = shortcut + RMS(res)*wf; hn = LN(hout)*w2+b2 ----------------
// (res already holds h + residual, updated in place by the last out_proj)
__global__ __launch_bounds__(256) void final_ln2_kernel(const float* __restrict__ res,
    const float* __restrict__ shortcut,
    const float* __restrict__ wf, const float* __restrict__ w2,
    const float* __restrict__ b2, float* __restrict__ hout,
    ushort* __restrict__ yb16)
{
    int lane = threadIdx.x & 63, wv = threadIdx.x >> 6;
    int row = blockIdx.x * 4 + wv;
    size_t base = (size_t)row * Dm + lane * 8;
    float v[8];
    *(float4*)(v)     = *(const float4*)(res + base);
    *(float4*)(v + 4) = *(const float4*)(res + base + 4);
    float ss = 0.f;
    #pragma unroll
    for (int q = 0; q < 8; ++q) ss += v[q] * v[q];
    ss = wave_sum(ss);
    float rs = rsqrtf(ss * (1.f / Dm) + 1e-5f);
    float sc[8], wf8[8];
    *(float4*)(sc)     = *(const float4*)(shortcut + base);
    *(float4*)(sc + 4) = *(const float4*)(shortcut + base + 4);
    *(float4*)(wf8)     = *(const float4*)(wf + lane * 8);
    *(float4*)(wf8 + 4) = *(const float4*)(wf + lane * 8 + 4);
    float t[8], s2 = 0.f, ss2 = 0.f;
    #pragma unroll
    for (int q = 0; q < 8; ++q) {
        t[q] = sc[q] + v[q] * rs * wf8[q];
        s2 += t[q]; ss2 += t[q] * t[q];
    }
    *(float4*)(hout + base)     = *(float4*)(t);
    *(float4*)(hout + base + 4) = *(float4*)(t + 4);
    s2 = wave_sum(s2); ss2 = wave_sum(ss2);
    float mu = s2 * (1.f / Dm);
    float rsig = rsqrtf(ss2 * (1.f / Dm) - mu * mu + 1e-5f);
    float w28[8], b28[8];
    *(float4*)(w28)     = *(const float4*)(w2 + lane * 8);
    *(float4*)(w28 + 4) = *(const float4*)(w2 + lane * 8 + 4);
    *(float4*)(b28)     = *(const float4*)(b2 + lane * 8);
    *(float4*)(b28 + 4) = *(const float4*)(b2 + lane * 8 + 4);
    bf16x8 ob;
    #pragma unroll
    for (int q = 0; q < 8; ++q) ob[q] = (short)f2bf((t[q] - mu) * rsig * w28[q] + b28[q]);
    *(bf16x8*)(yb16 + base) = ob;
}

// ---------------- MFMA bf16 GEMM: C(M,N) = A(M,K) * W(N,K)^T ----------------
// EPI: 1 = bf16 store; 2 = bias+gelu -> bf16; 4 = bias+addsrc -> f32;
//      5 = residual: Cout(=res fp32) += v, ssp[bx][row] = per-block partial sum of res_new^2
template<int BM, int BN, int BK, int EPI>
__global__ __launch_bounds__(256) void gemm_mfma(
    const ushort* __restrict__ A, int lda,
    const ushort* __restrict__ W, int K,
    void* __restrict__ Cout, int ldc,
    const float* __restrict__ bias, const float* __restrict__ addsrc,
    float* __restrict__ ssp)
{
    constexpr int ROWB  = BK * 2;
    constexpr int SMASK = (ROWB / 16) - 1;
    constexpr int KK    = BK / 32;
    constexpr int WM = BM / 2, WN = BN / 2;
    constexpr int FM = WM / 16, FN = WN / 16;
    constexpr int ISS_A = (BM * ROWB) / 4096;
    constexpr int ISS_W = (BN * ROWB) / 4096;

    __shared__ __align__(16) ushort As[BM * BK];
    __shared__ __align__(16) ushort Ws[BN * BK];
    __shared__ float ss_lds[2][BM];

    int tid = threadIdx.x;
    int wave = tid >> 6, lane = tid & 63;
    int wr = wave >> 1, wc = wave & 1;
    int l16 = lane & 15, lk = lane >> 4;
    int bm = blockIdx.y * BM, bn = blockIdx.x * BN;

    const ushort* srcA[ISS_A];
    const ushort* srcW[ISS_W];
    #pragma unroll
    for (int s = 0; s < ISS_A; ++s) {
        int off = s * 4096 + wave * 1024 + lane * 16;
        int row = off / ROWB;
        int slot = (off % ROWB) >> 4;
        int col = ((slot ^ (row & SMASK)) << 3);
        srcA[s] = A + (size_t)(bm + row) * lda + col;
    }
    #pragma unroll
    for (int s = 0; s < ISS_W; ++s) {
        int off = s * 4096 + wave * 1024 + lane * 16;
        int row = off / ROWB;
        int slot = (off % ROWB) >> 4;
        int col = ((slot ^ (row & SMASK)) << 3);
        srcW[s] = W + (size_t)(bn + row) * K + col;
    }
    int aoff[FM][KK], woff[FN][KK];
    #pragma unroll
    for (int i = 0; i < FM; ++i) {
        int row = wr * WM + i * 16 + l16;
        #pragma unroll
        for (int kk = 0; kk < KK; ++kk)
            aoff[i][kk] = row * BK + ((((kk << 2) | lk) ^ (row & SMASK)) << 3);
    }
    #pragma unroll
    for (int j = 0; j < FN; ++j) {
        int row = wc * WN + j * 16 + l16;
        #pragma unroll
        for (int kk = 0; kk < KK; ++kk)
            woff[j][kk] = row * BK + ((((kk << 2) | lk) ^ (row & SMASK)) << 3);
    }

    f32x4 acc[FM][FN] = {};

    for (int k0 = 0; k0 < K; k0 += BK) {
        #pragma unroll
        for (int s = 0; s < ISS_A; ++s)
            __builtin_amdgcn_global_load_lds(
                (const __attribute__((address_space(1))) void*)(srcA[s] + k0),
                (__attribute__((address_space(3))) void*)((char*)As + s * 4096 + wave * 1024),
                16, 0, 0);
        #pragma unroll
        for (int s = 0; s < ISS_W; ++s)
            __builtin_amdgcn_global_load_lds(
                (const __attribute__((address_space(1))) void*)(srcW[s] + k0),
                (__attribute__((address_space(3))) void*)((char*)Ws + s * 4096 + wave * 1024),
                16, 0, 0);
        __syncthreads();
        #pragma unroll
        for (int kk = 0; kk < KK; ++kk) {
            bf16x8 af[FM], wf[FN];
            #pragma unroll
            for (int i = 0; i < FM; ++i) af[i] = *(const bf16x8*)(As + aoff[i][kk]);
            #pragma unroll
            for (int j = 0; j < FN; ++j) wf[j] = *(const bf16x8*)(Ws + woff[j][kk]);
            #pragma unroll
            for (int i = 0; i < FM; ++i)
                #pragma unroll
                for (int j = 0; j < FN; ++j)
                    acc[i][j] = __builtin_amdgcn_mfma_f32_16x16x32_bf16(af[i], wf[j], acc[i][j], 0, 0, 0);
        }
        __syncthreads();
    }

    int orow0 = bm + wr * WM, ocol0 = bn + wc * WN;
    #pragma unroll
    for (int j = 0; j < FN; ++j) {
        int col = ocol0 + j * 16 + l16;
        float bj = 0.f;
        if constexpr (EPI == 2 || EPI == 4) bj = bias[col];
        #pragma unroll
        for (int i = 0; i < FM; ++i) {
            #pragma unroll
            for (int r = 0; r < 4; ++r) {
                int row = orow0 + i * 16 + lk * 4 + r;
                float v = acc[i][j][r];
                if constexpr (EPI == 1) {
                    ((ushort*)Cout)[(size_t)row * ldc + col] = f2bf(v);
                } else if constexpr (EPI == 2) {
                    ((ushort*)Cout)[(size_t)row * ldc + col] = f2bf(act_gelu(v + bj));
                } else if constexpr (EPI == 4) {
                    ((float*)Cout)[(size_t)row * ldc + col] = v + bj + addsrc[(size_t)row * ldc + col];
                } else if constexpr (EPI == 5) {
                    size_t idx = (size_t)row * ldc + col;
                    float nv = ((float*)Cout)[idx] + v;
                    ((float*)Cout)[idx] = nv;
                    float sq = nv * nv;
                    sq += __shfl_xor(sq, 1);
                    sq += __shfl_xor(sq, 2);
                    sq += __shfl_xor(sq, 4);
                    sq += __shfl_xor(sq, 8);
                    if (l16 == 0)
                        ss_lds[wc][wr * WM + i * 16 + lk * 4 + r] = sq;
                }
            }
        }
    }
    if constexpr (EPI == 5) {
        __syncthreads();
        if (tid < BM)
            ssp[(size_t)blockIdx.x * L_SEQ + bm + tid] = ss_lds[0][tid] + ss_lds[1][tid];
    }
}

// ---------------- in_proj with fused RMS-on-load: A = res(fp32) * rr[row] * bw[k] ----------------
// BM=128, BN=64, BK=128, K=512. rr from ssp (16 partials per row). W via global_load_lds.
__global__ __launch_bounds__(256) void gemm_rms_kernel(
    const float* __restrict__ res, const float* __restrict__ ssp,
    const float* __restrict__ bw, const ushort* __restrict__ W,
    ushort* __restrict__ Cout)
{
    constexpr int BM = 128, BN = 64, BK = 128, K = Dm;
    constexpr int ROWB  = BK * 2;            // 256
    constexpr int SMASK = 15;
    constexpr int KK    = 4;
    constexpr int WM = 64, WN = 32, FM = 4, FN = 2;
    constexpr int ISS_A = 8, ISS_W = 4;

    __shared__ __align__(16) ushort As[BM * BK];
    __shared__ __align__(16) ushort Ws[BN * BK];
    __shared__ float rr_lds[BM];

    int tid = threadIdx.x;
    int wave = tid >> 6, lane = tid & 63;
    int wr = wave >> 1, wc = wave & 1;
    int l16 = lane & 15, lk = lane >> 4;
    int bm = blockIdx.y * BM, bn = blockIdx.x * BN;

    // prologue: rr per row from 16 ssp partials
    if (tid < BM) {
        int row = bm + tid;
        float s = 0.f;
        #pragma unroll
        for (int x = 0; x < NXB; ++x) s += ssp[(size_t)x * L_SEQ + row];
        rr_lds[tid] = rsqrtf(s * (1.f / Dm) + 1e-5f);
    }

    const ushort* srcW[ISS_W];
    #pragma unroll
    for (int s = 0; s < ISS_W; ++s) {
        int off = s * 4096 + wave * 1024 + lane * 16;
        int row = off / ROWB;
        int slot = (off % ROWB) >> 4;
        int col = ((slot ^ (row & SMASK)) << 3);
        srcW[s] = W + (size_t)(bn + row) * K + col;
    }
    int aoff[FM][KK], woff[FN][KK];
    #pragma unroll
    for (int i = 0; i < FM; ++i) {
        int row = wr * WM + i * 16 + l16;
        #pragma unroll
        for (int kk = 0; kk < KK; ++kk)
            aoff[i][kk] = row * BK + ((((kk << 2) | lk) ^ (row & SMASK)) << 3);
    }
    #pragma unroll
    for (int j = 0; j < FN; ++j) {
        int row = wc * WN + j * 16 + l16;
        #pragma unroll
        for (int kk = 0; kk < KK; ++kk)
            woff[j][kk] = row * BK + ((((kk << 2) | lk) ^ (row & SMASK)) << 3);
    }
    __syncthreads();

    f32x4 acc[FM][FN] = {};

    for (int k0 = 0; k0 < K; k0 += BK) {
        #pragma unroll
        for (int s = 0; s < ISS_W; ++s)
            __builtin_amdgcn_global_load_lds(
                (const __attribute__((address_space(1))) void*)(srcW[s] + k0),
                (__attribute__((address_space(3))) void*)((char*)Ws + s * 4096 + wave * 1024),
                16, 0, 0);
        // A reg-staging: res fp32 -> *rr*bw -> bf16, swizzled ds_write
        #pragma unroll
        for (int s = 0; s < ISS_A; ++s) {
            int off = s * 4096 + wave * 1024 + lane * 16;
            int row = off >> 8;              // /256
            int slot = (off >> 4) & 15;
            int k = k0 + slot * 8;
            float rv[8], bw8[8];
            *(float4*)(rv)     = *(const float4*)(res + (size_t)(bm + row) * Dm + k);
            *(float4*)(rv + 4) = *(const float4*)(res + (size_t)(bm + row) * Dm + k + 4);
            *(float4*)(bw8)     = *(const float4*)(bw + k);
            *(float4*)(bw8 + 4) = *(const float4*)(bw + k + 4);
            float rr = rr_lds[row];
            bf16x8 o;
            #pragma unroll
            for (int q = 0; q < 8; ++q) o[q] = (short)f2bf(rv[q] * rr * bw8[q]);
            *(bf16x8*)(As + row * BK + ((slot ^ (row & SMASK)) << 3)) = o;
        }
        __syncthreads();
        #pragma unroll
        for (int kk = 0; kk < KK; ++kk) {
            bf16x8 af[FM], wf[FN];
            #pragma unroll
            for (int i = 0; i < FM; ++i) af[i] = *(const bf16x8*)(As + aoff[i][kk]);
            #pragma unroll
            for (int j = 0; j < FN; ++j) wf[j] = *(const bf16x8*)(Ws + woff[j][kk]);
            #pragma unroll
            for (int i = 0; i < FM; ++i)
                #pragma unroll
                for (int j = 0; j < FN; ++j)
                    acc[i][j] = __builtin_amdgcn_mfma_f32_16x16x32_bf16(af[i], wf[j], acc[i][j], 0, 0, 0);
        }
        __syncthreads();
    }

    int orow0 = bm + wr * WM, ocol0 = bn + wc * WN;
    #pragma unroll
    for (int j = 0; j < FN; ++j) {
        int col = ocol0 + j * 16 + l16;
        #pragma unroll
        for (int i = 0; i < FM; ++i)
            #pragma unroll
            for (int r = 0; r < 4; ++r) {
                int row = orow0 + i * 16 + lk * 4 + r;
                Cout[(size_t)row * (2 * DI) + col] = f2bf(acc[i][j][r]);
            }
    }
}

// ---------------- fused conv+silu + x_proj GEMM (split-K=8 over d; 256 blocks) ----------------
__global__ __launch_bounds__(256) void xproj_conv_kernel(
    const ushort* __restrict__ xz, const float* __restrict__ cw,
    const float* __restrict__ cb, const ushort* __restrict__ W,
    ushort* __restrict__ xc, float* __restrict__ part)
{
    constexpr int BM = 64, BN = 64, BK = 64;
    constexpr int ROWB  = BK * 2;
    constexpr int SMASK = (ROWB / 16) - 1;   // 7
    constexpr int KK    = BK / 32;           // 2
    constexpr int WM = 32, WN = 32, FM = 2, FN = 2;

    __shared__ __align__(16) ushort As[BM * BK];
    __shared__ __align__(16) ushort Ws[BN * BK];

    int tid = threadIdx.x;
    int wave = tid >> 6, lane = tid & 63;
    int wr = wave >> 1, wc = wave & 1;
    int l16 = lane & 15, lk = lane >> 4;
    int bm = blockIdx.y * BM;
    int z = blockIdx.z;
    int kbeg = z * (DI / KSX);

    const ushort* srcW[2];
    #pragma unroll
    for (int s = 0; s < 2; ++s) {
        int off = s * 4096 + wave * 1024 + lane * 16;
        int row = off / ROWB;
        int slot = (off % ROWB) >> 4;
        int col = ((slot ^ (row & SMASK)) << 3);
        srcW[s] = W + (size_t)row * DI + kbeg + col;
    }
    int aoff[FM][KK], woff[FN][KK];
    #pragma unroll
    for (int i = 0; i < FM; ++i) {
        int row = wr * WM + i * 16 + l16;
        #pragma unroll
        for (int kk = 0; kk < KK; ++kk)
            aoff[i][kk] = row * BK + ((((kk << 2) | lk) ^ (row & SMASK)) << 3);
    }
    #pragma unroll
    for (int j = 0; j < FN; ++j) {
        int row = wc * WN + j * 16 + l16;
        #pragma unroll
        for (int kk = 0; kk < KK; ++kk)
            woff[j][kk] = row * BK + ((((kk << 2) | lk) ^ (row & SMASK)) << 3);
    }

    f32x4 acc[FM][FN] = {};

    for (int k0 = 0; k0 < DI / KSX; k0 += BK) {
        #pragma unroll
        for (int s = 0; s < 2; ++s)
            __builtin_amdgcn_global_load_lds(
                (const __attribute__((address_space(1))) void*)(srcW[s] + k0),
                (__attribute__((address_space(3))) void*)((char*)Ws + s * 4096 + wave * 1024),
                16, 0, 0);
        #pragma unroll
        for (int s = 0; s < 2; ++s) {
            int off = s * 4096 + wave * 1024 + lane * 16;
            int row = off >> 7;
            int slot = (off >> 4) & 7;
            int t = bm + row;
            int dcol = kbeg + k0 + slot * 8;
            float a[8];
            float4 c4[8];
            #pragma unroll
            for (int q = 0; q < 8; ++q) {
                a[q] = cb[dcol + q];
                c4[q] = *(const float4*)(cw + (size_t)(dcol + q) * 4);
            }
            #pragma unroll
            for (int k = 0; k < 4; ++k) {
                int tt = t + k - 3;
                if (tt >= 0) {
                    bf16x8 xv = *(const bf16x8*)(xz + (size_t)tt * (2 * DI) + dcol);
                    #pragma unroll
                    for (int q = 0; q < 8; ++q) {
                        float wk = (k == 0) ? c4[q].x : (k == 1) ? c4[q].y
                                 : (k == 2) ? c4[q].z : c4[q].w;
                        a[q] = fmaf(wk, bf2f((ushort)xv[q]), a[q]);
                    }
                }
            }
            bf16x8 o;
            #pragma unroll
            for (int q = 0; q < 8; ++q) o[q] = (short)f2bf(silu_(a[q]));
            *(bf16x8*)(xc + (size_t)t * DI + dcol) = o;
            *(bf16x8*)(As + row * BK + ((slot ^ (row & SMASK)) << 3)) = o;
        }
        __syncthreads();
        #pragma unroll
        for (int kk = 0; kk < KK; ++kk) {
            bf16x8 af[FM], wf[FN];
            #pragma unroll
            for (int i = 0; i < FM; ++i) af[i] = *(const bf16x8*)(As + aoff[i][kk]);
            #pragma unroll
            for (int j = 0; j < FN; ++j) wf[j] = *(const bf16x8*)(Ws + woff[j][kk]);
            #pragma unroll
            for (int i = 0; i < FM; ++i)
                #pragma unroll
                for (int j = 0; j < FN; ++j)
                    acc[i][j] = __builtin_amdgcn_mfma_f32_16x16x32_bf16(af[i], wf[j], acc[i][j], 0, 0, 0);
        }
        __syncthreads();
    }

    float* coutf = part + (size_t)z * L_SEQ * 64;
    int orow0 = bm + wr * WM, ocol0 = wc * WN;
    #pragma unroll
    for (int j = 0; j < FN; ++j) {
        int col = ocol0 + j * 16 + l16;
        #pragma unroll
        for (int i = 0; i < FM; ++i)
            #pragma unroll
            for (int r = 0; r < 4; ++r) {
                int row = orow0 + i * 16 + lk * 4 + r;
                coutf[(size_t)row * 64 + col] = acc[i][j][r];
            }
    }
}

// ---------------- 3-phase chunked SSM scan, 16 n-states per thread ----------------
__global__ __launch_bounds__(256) void scan_chunk_kernel(
    const float* __restrict__ part, const ushort* __restrict__ u,
    const ushort* __restrict__ wdt, const float* __restrict__ dtb,
    const float* __restrict__ A_log,
    float* __restrict__ hend, float* __restrict__ aprod,
    ushort* __restrict__ delta_bf)
{
    __shared__ float sdt[LC][32];
    __shared__ float bsm[LC][16];
    int tid = threadIdx.x;
    int c = blockIdx.x;
    int d = blockIdx.y * 256 + tid;
    int t0 = c * LC;
    const int S = L_SEQ * 64;
    for (int i = tid; i < LC * 48; i += 256) {
        int tt = i / 48, cc = i % 48;
        int idx = (t0 + tt) * 64 + cc;
        float s = 0.f;
        #pragma unroll
        for (int p = 0; p < KSX; ++p) s += part[idx + p * S];
        if (cc < 32) sdt[tt][cc] = s; else bsm[tt][cc - 32] = s;
    }
    bf16x8 wd[4];
    #pragma unroll
    for (int p = 0; p < 4; ++p) wd[p] = *(const bf16x8*)(wdt + (size_t)d * 32 + p * 8);
    float bd = dtb[d];
    float A2[16];
    {
        float a[16];
        #pragma unroll
        for (int q = 0; q < 4; ++q)
            *(float4*)(a + q * 4) = ((const float4*)(A_log + (size_t)d * 16))[q];
        #pragma unroll
        for (int n = 0; n < 16; ++n)
            A2[n] = -__expf(a[n]) * 1.44269504f;
    }
    float h[16], ap[16];
    #pragma unroll
    for (int n = 0; n < 16; ++n) { h[n] = 0.f; ap[n] = 1.f; }
    __syncthreads();
    for (int tt = 0; tt < LC; ++tt) {
        int t = t0 + tt;
        float dtv = bd;
        #pragma unroll
        for (int p = 0; p < 4; ++p)
            #pragma unroll
            for (int e = 0; e < 8; ++e)
                dtv = fmaf(sdt[tt][p * 8 + e], bf2f((ushort)wd[p][e]), dtv);
        ushort dbf = f2bf(act_softplus(dtv));
        delta_bf[(size_t)t * DI + d] = dbf;
        float dt_ = bf2f(dbf);
        float du = dt_ * bf2f(u[(size_t)t * DI + d]);
        #pragma unroll
        for (int n = 0; n < 16; ++n) {
            float dA = exp2f(dt_ * A2[n]);
            h[n] = fmaf(dA, h[n], du * bsm[tt][n]);
            ap[n] *= dA;
        }
    }
    size_t base = ((size_t)c * DI + d) * 16;
    #pragma unroll
    for (int q = 0; q < 4; ++q) {
        ((float4*)(hend + base))[q]  = *(float4*)(h + q * 4);
        ((float4*)(aprod + base))[q] = *(float4*)(ap + q * 4);
    }
}

// Phase B: serial over chunks, j-in-lanes coalesced, float4 per thread, unroll-8.
__global__ __launch_bounds__(64) void chunk_prefix_kernel(
    const float* __restrict__ hend, float* __restrict__ aprod_hin)
{
    int j4 = (blockIdx.x * 64 + threadIdx.x) * 4;   // over DI*16 = 16384
    float4 h = { 0.f, 0.f, 0.f, 0.f };
    for (int cg = 0; cg < CH; cg += 8) {
        float4 ap[8], he[8];
        #pragma unroll
        for (int q = 0; q < 8; ++q) {
            size_t o = (size_t)(cg + q) * (DI * Nst) + j4;
            ap[q] = *(const float4*)(aprod_hin + o);
            he[q] = *(const float4*)(hend + o);
        }
        #pragma unroll
        for (int q = 0; q < 8; ++q) {
            size_t o = (size_t)(cg + q) * (DI * Nst) + j4;
            *(float4*)(aprod_hin + o) = h;
            h.x = fmaf(ap[q].x, h.x, he[q].x);
            h.y = fmaf(ap[q].y, h.y, he[q].y);
            h.z = fmaf(ap[q].z, h.z, he[q].z);
            h.w = fmaf(ap[q].w, h.w, he[q].w);
        }
    }
}

// Phase C: stages B,C sums from partials; reads delta_bf written by phase A.
__global__ __launch_bounds__(256) void scan_apply_kernel(
    const float* __restrict__ part, const ushort* __restrict__ delta,
    const ushort* __restrict__ u, const float* __restrict__ A_log,
    const float* __restrict__ Dp, const ushort* __restrict__ xz,
    const float* __restrict__ hin, ushort* __restrict__ y)
{
    __shared__ float bsm[LC][16], csm[LC][16];
    int tid = threadIdx.x;
    int c = blockIdx.x;
    int d = blockIdx.y * 256 + tid;
    int t0 = c * LC;
    const int S = L_SEQ * 64;
    for (int i = tid; i < LC * 32; i += 256) {
        int tt = i >> 5, k = i & 31;
        int idx = (t0 + tt) * 64 + 32 + k;
        float s = 0.f;
        #pragma unroll
        for (int p = 0; p < KSX; ++p) s += part[idx + p * S];
        if (k < 16) bsm[tt][k] = s; else csm[tt][k - 16] = s;
    }
    float A2[16];
    {
        float a[16];
        #pragma unroll
        for (int q = 0; q < 4; ++q)
            *(float4*)(a + q * 4) = ((const float4*)(A_log + (size_t)d * 16))[q];
        #pragma unroll
        for (int n = 0; n < 16; ++n)
            A2[n] = -__expf(a[n]) * 1.44269504f;
    }
    float h[16];
    size_t base = ((size_t)c * DI + d) * 16;
    #pragma unroll
    for (int q = 0; q < 4; ++q)
        *(float4*)(h + q * 4) = ((const float4*)(hin + base))[q];
    float Dval = Dp[d];
    __syncthreads();
    for (int tt = 0; tt < LC; ++tt) {
        int t = t0 + tt;
        float dt_ = bf2f(delta[(size_t)t * DI + d]);
        float u_  = bf2f(u[(size_t)t * DI + d]);
        float du  = dt_ * u_;
        float acc = 0.f;
        #pragma unroll
        for (int n = 0; n < 16; ++n) {
            float dA = exp2f(dt_ * A2[n]);
            h[n] = fmaf(dA, h[n], du * bsm[tt][n]);
            acc = fmaf(h[n], csm[tt][n], acc);
        }
        float zv = bf2f(xz[(size_t)t * (2 * DI) + DI + d]);
        y[(size_t)t * DI + d] = f2bf((acc + u_ * Dval) * silu_(zv));
    }
}

extern "C" void kernel_launch(void* const* d_in, const int* in_sizes, int n_in,
                              void* d_out, int out_size, void* d_ws, size_t ws_size,
                              hipStream_t stream)
{
    const float* hidden     = (const float*)d_in[0];
    const float* ln1_w      = (const float*)d_in[1];
    const float* ln1_b      = (const float*)d_in[2];
    const float* in_proj_w  = (const float*)d_in[3];
    const float* conv_w     = (const float*)d_in[4];
    const float* conv_b     = (const float*)d_in[5];
    const float* x_proj_w   = (const float*)d_in[6];
    const float* dt_proj_w  = (const float*)d_in[7];
    const float* dt_proj_b  = (const float*)d_in[8];
    const float* A_log      = (const float*)d_in[9];
    const float* D_param    = (const float*)d_in[10];
    const float* out_proj_w = (const float*)d_in[11];
    const float* block_norm_w = (const float*)d_in[12];
    const float* norm_f_w   = (const float*)d_in[13];
    const float* ln2_w      = (const float*)d_in[14];
    const float* ln2_b      = (const float*)d_in[15];
    const float* fc1_w      = (const float*)d_in[16];
    const float* fc1_b      = (const float*)d_in[17];
    const float* fc2_w      = (const float*)d_in[18];
    const float* fc2_b      = (const float*)d_in[19];

    char* P = (char*)d_ws;
    auto alloc = [&](size_t bytes) { char* r = P; P += (bytes + 255) & ~(size_t)255; return r; };
    float* hout   = (float*)alloc((size_t)L_SEQ * Dm * 4);
    float* res    = (float*)alloc((size_t)L_SEQ * Dm * 4);
    float* ssp    = (float*)alloc((size_t)NXB * L_SEQ * 4);         // 128KB partial row ss
    float* part   = (float*)alloc((size_t)KSX * L_SEQ * 64 * 4);    // x_proj split-K partials
    float* hend   = (float*)alloc((size_t)CH * DI * Nst * 4);       // 4MB
    float* aprod  = (float*)alloc((size_t)CH * DI * Nst * 4);       // 4MB; becomes hin in place
    ushort* delta_bf = (ushort*)alloc((size_t)L_SEQ * DI * 2);
    ushort* hn_bf = (ushort*)alloc((size_t)L_SEQ * Dm * 2);
    ushort* xz_bf = (ushort*)alloc((size_t)L_SEQ * 2 * DI * 2);
    ushort* xc_bf = (ushort*)alloc((size_t)L_SEQ * DI * 2);
    ushort* yb_bf = (ushort*)alloc((size_t)L_SEQ * DI * 2);
    ushort* w_in  = (ushort*)alloc((size_t)NL * 2 * DI * Dm * 2);
    ushort* w_out = (ushort*)alloc((size_t)NL * Dm * DI * 2);
    ushort* w_x   = (ushort*)alloc((size_t)NL * 64 * DI * 2);
    ushort* w_dt  = (ushort*)alloc((size_t)NL * DI * Rr * 2);
    ushort* w_fc1 = (ushort*)alloc((size_t)(4 * Dm) * Dm * 2);
    ushort* w_fc2 = (ushort*)alloc((size_t)Dm * (4 * Dm) * 2);
    float* out  = (float*)d_out;

    // setup: weight casts + LN1 -> res + ssp seed (layer-0 RMS partials)
    {
        int n0 = NL * 2 * DI * Dm / 4, n1 = NL * Dm * DI / 4, n2 = NL * 64 * DI / 4;
        int n3 = NL * DI * Rr / 4, n4_ = 4 * Dm * Dm / 4, n5 = Dm * 4 * Dm / 4;
        int tot = n0 + n1 + n2 + n3 + n4_ + n5;
        int grid = 512 + (tot + 255) / 256;
        setup_kernel<<<grid, 256, 0, stream>>>(
            in_proj_w, w_in, n0, out_proj_w, w_out, n1, x_proj_w, w_x, n2,
            dt_proj_w, w_dt, n3, fc1_w, w_fc1, n4_, fc2_w, w_fc2, n5,
            hidden, ln1_w, ln1_b, res, ssp);
    }

    dim3 gscan(CH, DI / 256);   // 64 x 4 = 256 blocks
    for (int i = 0; i < NL; ++i) {
        // in_proj with fused RMS-on-load: M=2048 N=2048 K=512 -> bf16 xz
        gemm_rms_kernel<<<dim3(2 * DI / 64, L_SEQ / 128), 256, 0, stream>>>(
            res, ssp, block_norm_w + i * Dm, w_in + (size_t)i * 2 * DI * Dm, xz_bf);
        // fused conv+silu + x_proj split-K=8 -> xc (bf16) + fp32 partials (256 blocks)
        xproj_conv_kernel<<<dim3(1, L_SEQ / 64, KSX), 256, 0, stream>>>(
            xz_bf, conv_w + i * DI * Kc, conv_b + i * DI,
            w_x + (size_t)i * 64 * DI, xc_bf, part);
        // 3-phase chunked scan (phase A finishes x_proj reduce + dt_proj)
        scan_chunk_kernel<<<gscan, 256, 0, stream>>>(part, xc_bf,
                                        w_dt + (size_t)i * DI * Rr, dt_proj_b + i * DI,
                                        A_log + (size_t)i * DI * Nst, hend, aprod, delta_bf);
        chunk_prefix_kernel<<<(DI * Nst) / 256, 64, 0, stream>>>(hend, aprod);
        scan_apply_kernel<<<gscan, 256, 0, stream>>>(part, delta_bf, xc_bf,
                                        A_log + (size_t)i * DI * Nst,
                                        D_param + i * DI, xz_bf, aprod, yb_bf);
        // out_proj: M=2048 N=512 K=1024; res += h (fp32) + ssp row partials
        gemm_mfma<64, 32, 128, 5><<<dim3(Dm / 32, L_SEQ / 64), 256, 0, stream>>>(
            yb_bf, DI, w_out + (size_t)i * Dm * DI, DI, res, Dm, nullptr, nullptr, ssp);
    }

    final_ln2_kernel<<<L_SEQ / 4, 256, 0, stream>>>(res, hidden, norm_f_w,
                                                ln2_w, ln2_b, hout, hn_bf);
    // fc1: M=2048 N=2048 K=512, bias+gelu -> bf16  (128x64 tile)
    gemm_mfma<128, 64, 128, 2><<<dim3(2048 / 64, L_SEQ / 128), 256, 0, stream>>>(
        hn_bf, Dm, w_fc1, Dm, xz_bf, 2048, fc1_b, nullptr, nullptr);
    // fc2: M=2048 N=512 K=2048, bias+add(hout) -> fp32 out  (64x32 tile)
    gemm_mfma<64, 32, 128, 4><<<dim3(Dm / 32, L_SEQ / 64), 256, 0, stream>>>(
        xz_bf, 2048, w_fc2, 2048, out, Dm, fc2_b, hout, nullptr);
}

// Round 17
// 402.829 us; speedup vs baseline: 1.1907x; 1.1907x over previous
//
#include <hip/hip_runtime.h>
#include <hip/hip_bf16.h>
#include <math.h>

#define L_SEQ 2048
#define Dm    512
#define DI    1024
#define Nst   16
#define Kc    4
#define Rr    32
#define NL    4
#define CH    128
#define LC    (L_SEQ / CH)   // 16
#define KSX   8              // x_proj split-K

typedef __attribute__((ext_vector_type(8))) short bf16x8;
typedef __attribute__((ext_vector_type(4))) float f32x4;

// ---------------- helpers ----------------
__device__ __forceinline__ float act_softplus(float x) {
    return fmaxf(x, 0.f) + log1pf(__expf(-fabsf(x)));
}
__device__ __forceinline__ float act_gelu(float x) {
    float c = 0.7978845608028654f * (x + 0.044715f * x * x * x);
    float t = 1.f - 2.f / (__expf(2.f * c) + 1.f);   // tanh(c)
    return 0.5f * x * (1.f + t);
}
__device__ __forceinline__ float silu_(float x) {
    return x / (1.f + __expf(-x));
}
__device__ __forceinline__ ushort f2bf(float f) {
    union { float f; unsigned u; } c; c.f = f;
    unsigned r = c.u + 0x7fffu + ((c.u >> 16) & 1u);
    return (ushort)(r >> 16);
}
__device__ __forceinline__ float bf2f(ushort u) {
    union { unsigned u; float f; } c; c.u = ((unsigned)u) << 16;
    return c.f;
}
__device__ __forceinline__ float wave_sum(float v) {
    #pragma unroll
    for (int off = 32; off; off >>= 1) v += __shfl_xor(v, off);
    return v;
}

// ---------------- setup: all weight casts + fused LN1/RMS0 (one kernel) ----------------
__global__ __launch_bounds__(256) void setup_kernel(
    const float* __restrict__ s0, ushort* __restrict__ d0, int n0,
    const float* __restrict__ s1, ushort* __restrict__ d1, int n1,
    const float* __restrict__ s2, ushort* __restrict__ d2, int n2,
    const float* __restrict__ s3, ushort* __restrict__ d3, int n3,
    const float* __restrict__ s4, ushort* __restrict__ d4, int n4_,
    const float* __restrict__ s5, ushort* __restrict__ d5, int n5,
    const float* __restrict__ x, const float* __restrict__ w,
    const float* __restrict__ b, const float* __restrict__ rw,
    float* __restrict__ res, ushort* __restrict__ hn_bf)
{
    if (blockIdx.x < 512) {
        int lane = threadIdx.x & 63, wv = threadIdx.x >> 6;
        int row = blockIdx.x * 4 + wv;
        size_t base = (size_t)row * Dm + lane * 8;
        float v[8];
        *(float4*)(v)     = *(const float4*)(x + base);
        *(float4*)(v + 4) = *(const float4*)(x + base + 4);
        float s = 0.f, ss = 0.f;
        #pragma unroll
        for (int q = 0; q < 8; ++q) { s += v[q]; ss += v[q] * v[q]; }
        s = wave_sum(s); ss = wave_sum(ss);
        float mu = s * (1.f / Dm);
        float rs = rsqrtf(ss * (1.f / Dm) - mu * mu + 1e-5f);
        float wv8[8], bv8[8], rv8[8];
        *(float4*)(wv8)     = *(const float4*)(w + lane * 8);
        *(float4*)(wv8 + 4) = *(const float4*)(w + lane * 8 + 4);
        *(float4*)(bv8)     = *(const float4*)(b + lane * 8);
        *(float4*)(bv8 + 4) = *(const float4*)(b + lane * 8 + 4);
        *(float4*)(rv8)     = *(const float4*)(rw + lane * 8);
        *(float4*)(rv8 + 4) = *(const float4*)(rw + lane * 8 + 4);
        float o[8], ss2 = 0.f;
        #pragma unroll
        for (int q = 0; q < 8; ++q) {
            o[q] = (v[q] - mu) * rs * wv8[q] + bv8[q];
            ss2 += o[q] * o[q];
        }
        *(float4*)(res + base)     = *(float4*)(o);
        *(float4*)(res + base + 4) = *(float4*)(o + 4);
        ss2 = wave_sum(ss2);
        float rr = rsqrtf(ss2 * (1.f / Dm) + 1e-5f);
        bf16x8 hb;
        #pragma unroll
        for (int q = 0; q < 8; ++q) hb[q] = (short)f2bf(o[q] * rr * rv8[q]);
        *(bf16x8*)(hn_bf + base) = hb;
        return;
    }
    int i = (blockIdx.x - 512) * 256 + threadIdx.x;
    const float* s; ushort* d;
    if (i < n0) { s = s0; d = d0; }
    else { i -= n0; if (i < n1) { s = s1; d = d1; }
    else { i -= n1; if (i < n2) { s = s2; d = d2; }
    else { i -= n2; if (i < n3) { s = s3; d = d3; }
    else { i -= n3; if (i < n4_) { s = s4; d = d4; }
    else { i -= n4_; if (i < n5) { s = s5; d = d5; } else return; } } } } }
    float4 v = ((const float4*)s)[i];
    ushort4 o;
    o.x = f2bf(v.x); o.y = f2bf(v.y); o.z = f2bf(v.z); o.w = f2bf(v.w);
    ((ushort4*)d)[i] = o;
}

// ---------------- residual add + RMSNorm: res += h(bf16); hn = RMS(res)*w ----------------
__global__ __launch_bounds__(256) void add_rms_kernel(const ushort* __restrict__ hb,
    float* __restrict__ res, const float* __restrict__ w, ushort* __restrict__ rms_out)
{
    int lane = threadIdx.x & 63, wv = threadIdx.x >> 6;
    int row = blockIdx.x * 4 + wv;
    size_t base = (size_t)row * Dm + lane * 8;
    bf16x8 hv = *(const bf16x8*)(hb + base);
    float v[8];
    *(float4*)(v)     = *(const float4*)(res + base);
    *(float4*)(v + 4) = *(const float4*)(res + base + 4);
    float ss = 0.f;
    #pragma unroll
    for (int q = 0; q < 8; ++q) {
        v[q] += bf2f((ushort)hv[q]);
        ss += v[q] * v[q];
    }
    *(float4*)(res + base)     = *(float4*)(v);
    *(float4*)(res + base + 4) = *(float4*)(v + 4);
    ss = wave_sum(ss);
    float rr = rsqrtf(ss * (1.f / Dm) + 1e-5f);
    float wv8[8];
    *(float4*)(wv8)     = *(const float4*)(w + lane * 8);
    *(float4*)(wv8 + 4) = *(const float4*)(w + lane * 8 + 4);
    bf16x8 ob;
    #pragma unroll
    for (int q = 0; q < 8; ++q) ob[q] = (short)f2bf(v[q] * rr * wv8[q]);
    *(bf16x8*)(rms_out + base) = ob;
}

// ---------------- fused: hout = shortcut + RMS(h+res)*wf; hn = LN(hout)*w2+b2 ----------------
__global__ __launch_bounds__(256) void final_ln2_kernel(const ushort* __restrict__ hb,
    const float* __restrict__ res, const float* __restrict__ shortcut,
    const float* __restrict__ wf, const float* __restrict__ w2,
    const float* __restrict__ b2, float* __restrict__ hout,
    ushort* __restrict__ yb16)
{
    int lane = threadIdx.x & 63, wv = threadIdx.x >> 6;
    int row = blockIdx.x * 4 + wv;
    size_t base = (size_t)row * Dm + lane * 8;
    bf16x8 hv = *(const bf16x8*)(hb + base);
    float v[8];
    *(float4*)(v)     = *(const float4*)(res + base);
    *(float4*)(v + 4) = *(const float4*)(res + base + 4);
    float ss = 0.f;
    #pragma unroll
    for (int q = 0; q < 8; ++q) {
        v[q] += bf2f((ushort)hv[q]);
        ss += v[q] * v[q];
    }
    ss = wave_sum(ss);
    float rs = rsqrtf(ss * (1.f / Dm) + 1e-5f);
    float sc[8], wf8[8];
    *(float4*)(sc)     = *(const float4*)(shortcut + base);
    *(float4*)(sc + 4) = *(const float4*)(shortcut + base + 4);
    *(float4*)(wf8)     = *(const float4*)(wf + lane * 8);
    *(float4*)(wf8 + 4) = *(const float4*)(wf + lane * 8 + 4);
    float t[8], s2 = 0.f, ss2 = 0.f;
    #pragma unroll
    for (int q = 0; q < 8; ++q) {
        t[q] = sc[q] + v[q] * rs * wf8[q];
        s2 += t[q]; ss2 += t[q] * t[q];
    }
    *(float4*)(hout + base)     = *(float4*)(t);
    *(float4*)(hout + base + 4) = *(float4*)(t + 4);
    s2 = wave_sum(s2); ss2 = wave_sum(ss2);
    float mu = s2 * (1.f / Dm);
    float rsig = rsqrtf(ss2 * (1.f / Dm) - mu * mu + 1e-5f);
    float w28[8], b28[8];
    *(float4*)(w28)     = *(const float4*)(w2 + lane * 8);
    *(float4*)(w28 + 4) = *(const float4*)(w2 + lane * 8 + 4);
    *(float4*)(b28)     = *(const float4*)(b2 + lane * 8);
    *(float4*)(b28 + 4) = *(const float4*)(b2 + lane * 8 + 4);
    bf16x8 ob;
    #pragma unroll
    for (int q = 0; q < 8; ++q) ob[q] = (short)f2bf((t[q] - mu) * rsig * w28[q] + b28[q]);
    *(bf16x8*)(yb16 + base) = ob;
}

// ---------------- MFMA bf16 GEMM: C(M,N) = A(M,K) * W(N,K)^T ----------------
// EPI: 1 = bf16 store; 2 = bias+gelu -> bf16; 4 = bias+addsrc -> f32
template<int BM, int BN, int BK, int EPI>
__global__ __launch_bounds__(256) void gemm_mfma(
    const ushort* __restrict__ A, int lda,
    const ushort* __restrict__ W, int K,
    void* __restrict__ Cout, int ldc,
    const float* __restrict__ bias, const float* __restrict__ addsrc)
{
    constexpr int ROWB  = BK * 2;
    constexpr int SMASK = (ROWB / 16) - 1;
    constexpr int KK    = BK / 32;
    constexpr int WM = BM / 2, WN = BN / 2;
    constexpr int FM = WM / 16, FN = WN / 16;
    constexpr int ISS_A = (BM * ROWB) / 4096;
    constexpr int ISS_W = (BN * ROWB) / 4096;

    __shared__ __align__(16) ushort As[BM * BK];
    __shared__ __align__(16) ushort Ws[BN * BK];

    int tid = threadIdx.x;
    int wave = tid >> 6, lane = tid & 63;
    int wr = wave >> 1, wc = wave & 1;
    int l16 = lane & 15, lk = lane >> 4;
    int bm = blockIdx.y * BM, bn = blockIdx.x * BN;

    const ushort* srcA[ISS_A];
    const ushort* srcW[ISS_W];
    #pragma unroll
    for (int s = 0; s < ISS_A; ++s) {
        int off = s * 4096 + wave * 1024 + lane * 16;
        int row = off / ROWB;
        int slot = (off % ROWB) >> 4;
        int col = ((slot ^ (row & SMASK)) << 3);
        srcA[s] = A + (size_t)(bm + row) * lda + col;
    }
    #pragma unroll
    for (int s = 0; s < ISS_W; ++s) {
        int off = s * 4096 + wave * 1024 + lane * 16;
        int row = off / ROWB;
        int slot = (off % ROWB) >> 4;
        int col = ((slot ^ (row & SMASK)) << 3);
        srcW[s] = W + (size_t)(bn + row) * K + col;
    }
    int aoff[FM][KK], woff[FN][KK];
    #pragma unroll
    for (int i = 0; i < FM; ++i) {
        int row = wr * WM + i * 16 + l16;
        #pragma unroll
        for (int kk = 0; kk < KK; ++kk)
            aoff[i][kk] = row * BK + ((((kk << 2) | lk) ^ (row & SMASK)) << 3);
    }
    #pragma unroll
    for (int j = 0; j < FN; ++j) {
        int row = wc * WN + j * 16 + l16;
        #pragma unroll
        for (int kk = 0; kk < KK; ++kk)
            woff[j][kk] = row * BK + ((((kk << 2) | lk) ^ (row & SMASK)) << 3);
    }

    f32x4 acc[FM][FN] = {};

    for (int k0 = 0; k0 < K; k0 += BK) {
        #pragma unroll
        for (int s = 0; s < ISS_A; ++s)
            __builtin_amdgcn_global_load_lds(
                (const __attribute__((address_space(1))) void*)(srcA[s] + k0),
                (__attribute__((address_space(3))) void*)((char*)As + s * 4096 + wave * 1024),
                16, 0, 0);
        #pragma unroll
        for (int s = 0; s < ISS_W; ++s)
            __builtin_amdgcn_global_load_lds(
                (const __attribute__((address_space(1))) void*)(srcW[s] + k0),
                (__attribute__((address_space(3))) void*)((char*)Ws + s * 4096 + wave * 1024),
                16, 0, 0);
        __syncthreads();
        #pragma unroll
        for (int kk = 0; kk < KK; ++kk) {
            bf16x8 af[FM], wf[FN];
            #pragma unroll
            for (int i = 0; i < FM; ++i) af[i] = *(const bf16x8*)(As + aoff[i][kk]);
            #pragma unroll
            for (int j = 0; j < FN; ++j) wf[j] = *(const bf16x8*)(Ws + woff[j][kk]);
            #pragma unroll
            for (int i = 0; i < FM; ++i)
                #pragma unroll
                for (int j = 0; j < FN; ++j)
                    acc[i][j] = __builtin_amdgcn_mfma_f32_16x16x32_bf16(af[i], wf[j], acc[i][j], 0, 0, 0);
        }
        __syncthreads();
    }

    int orow0 = bm + wr * WM, ocol0 = bn + wc * WN;
    #pragma unroll
    for (int j = 0; j < FN; ++j) {
        int col = ocol0 + j * 16 + l16;
        float bj = 0.f;
        if constexpr (EPI == 2 || EPI == 4) bj = bias[col];
        #pragma unroll
        for (int i = 0; i < FM; ++i) {
            #pragma unroll
            for (int r = 0; r < 4; ++r) {
                int row = orow0 + i * 16 + lk * 4 + r;
                float v = acc[i][j][r];
                if constexpr (EPI == 1) {
                    ((ushort*)Cout)[(size_t)row * ldc + col] = f2bf(v);
                } else if constexpr (EPI == 2) {
                    ((ushort*)Cout)[(size_t)row * ldc + col] = f2bf(act_gelu(v + bj));
                } else if constexpr (EPI == 4) {
                    ((float*)Cout)[(size_t)row * ldc + col] = v + bj + addsrc[(size_t)row * ldc + col];
                }
            }
        }
    }
}

// ---------------- fused conv+silu + x_proj GEMM (split-K=8 over d; 256 blocks) ----------------
__global__ __launch_bounds__(256) void xproj_conv_kernel(
    const ushort* __restrict__ xz, const float* __restrict__ cw,
    const float* __restrict__ cb, const ushort* __restrict__ W,
    ushort* __restrict__ xc, float* __restrict__ part)
{
    constexpr int BM = 64, BN = 64, BK = 64;
    constexpr int ROWB  = BK * 2;            // 128
    constexpr int SMASK = (ROWB / 16) - 1;   // 7
    constexpr int KK    = BK / 32;           // 2
    constexpr int WM = 32, WN = 32, FM = 2, FN = 2;

    __shared__ __align__(16) ushort As[BM * BK];
    __shared__ __align__(16) ushort Ws[BN * BK];

    int tid = threadIdx.x;
    int wave = tid >> 6, lane = tid & 63;
    int wr = wave >> 1, wc = wave & 1;
    int l16 = lane & 15, lk = lane >> 4;
    int bm = blockIdx.y * BM;
    int z = blockIdx.z;
    int kbeg = z * (DI / KSX);               // 128 per split

    const ushort* srcW[2];
    #pragma unroll
    for (int s = 0; s < 2; ++s) {
        int off = s * 4096 + wave * 1024 + lane * 16;
        int row = off / ROWB;
        int slot = (off % ROWB) >> 4;
        int col = ((slot ^ (row & SMASK)) << 3);
        srcW[s] = W + (size_t)row * DI + kbeg + col;
    }
    int aoff[FM][KK], woff[FN][KK];
    #pragma unroll
    for (int i = 0; i < FM; ++i) {
        int row = wr * WM + i * 16 + l16;
        #pragma unroll
        for (int kk = 0; kk < KK; ++kk)
            aoff[i][kk] = row * BK + ((((kk << 2) | lk) ^ (row & SMASK)) << 3);
    }
    #pragma unroll
    for (int j = 0; j < FN; ++j) {
        int row = wc * WN + j * 16 + l16;
        #pragma unroll
        for (int kk = 0; kk < KK; ++kk)
            woff[j][kk] = row * BK + ((((kk << 2) | lk) ^ (row & SMASK)) << 3);
    }

    f32x4 acc[FM][FN] = {};

    for (int k0 = 0; k0 < DI / KSX; k0 += BK) {
        #pragma unroll
        for (int s = 0; s < 2; ++s)
            __builtin_amdgcn_global_load_lds(
                (const __attribute__((address_space(1))) void*)(srcW[s] + k0),
                (__attribute__((address_space(3))) void*)((char*)Ws + s * 4096 + wave * 1024),
                16, 0, 0);
        #pragma unroll
        for (int s = 0; s < 2; ++s) {
            int off = s * 4096 + wave * 1024 + lane * 16;
            int row = off >> 7;              // /128
            int slot = (off >> 4) & 7;
            int t = bm + row;
            int dcol = kbeg + k0 + slot * 8;
            float a[8];
            float4 c4[8];
            #pragma unroll
            for (int q = 0; q < 8; ++q) {
                a[q] = cb[dcol + q];
                c4[q] = *(const float4*)(cw + (size_t)(dcol + q) * 4);
            }
            #pragma unroll
            for (int k = 0; k < 4; ++k) {
                int tt = t + k - 3;
                if (tt >= 0) {
                    bf16x8 xv = *(const bf16x8*)(xz + (size_t)tt * (2 * DI) + dcol);
                    #pragma unroll
                    for (int q = 0; q < 8; ++q) {
                        float wk = (k == 0) ? c4[q].x : (k == 1) ? c4[q].y
                                 : (k == 2) ? c4[q].z : c4[q].w;
                        a[q] = fmaf(wk, bf2f((ushort)xv[q]), a[q]);
                    }
                }
            }
            bf16x8 o;
            #pragma unroll
            for (int q = 0; q < 8; ++q) o[q] = (short)f2bf(silu_(a[q]));
            *(bf16x8*)(xc + (size_t)t * DI + dcol) = o;
            *(bf16x8*)(As + row * BK + ((slot ^ (row & SMASK)) << 3)) = o;
        }
        __syncthreads();
        #pragma unroll
        for (int kk = 0; kk < KK; ++kk) {
            bf16x8 af[FM], wf[FN];
            #pragma unroll
            for (int i = 0; i < FM; ++i) af[i] = *(const bf16x8*)(As + aoff[i][kk]);
            #pragma unroll
            for (int j = 0; j < FN; ++j) wf[j] = *(const bf16x8*)(Ws + woff[j][kk]);
            #pragma unroll
            for (int i = 0; i < FM; ++i)
                #pragma unroll
                for (int j = 0; j < FN; ++j)
                    acc[i][j] = __builtin_amdgcn_mfma_f32_16x16x32_bf16(af[i], wf[j], acc[i][j], 0, 0, 0);
        }
        __syncthreads();
    }

    float* coutf = part + (size_t)z * L_SEQ * 64;
    int orow0 = bm + wr * WM, ocol0 = wc * WN;
    #pragma unroll
    for (int j = 0; j < FN; ++j) {
        int col = ocol0 + j * 16 + l16;
        #pragma unroll
        for (int i = 0; i < FM; ++i)
            #pragma unroll
            for (int r = 0; r < 4; ++r) {
                int row = orow0 + i * 16 + lk * 4 + r;
                coutf[(size_t)row * 64 + col] = acc[i][j][r];
            }
    }
}

// ---------------- 3-phase chunked SSM scan, 16 n-states per thread ----------------
__global__ __launch_bounds__(256) void scan_chunk_kernel(
    const float* __restrict__ part, const ushort* __restrict__ u,
    const ushort* __restrict__ wdt, const float* __restrict__ dtb,
    const float* __restrict__ A_log,
    float* __restrict__ hend, float* __restrict__ aprod,
    ushort* __restrict__ delta_bf)
{
    __shared__ float sdt[LC][32];
    __shared__ float bsm[LC][16];
    int tid = threadIdx.x;
    int c = blockIdx.x;
    int d = blockIdx.y * 256 + tid;
    int t0 = c * LC;
    const int S = L_SEQ * 64;
    for (int i = tid; i < LC * 48; i += 256) {
        int tt = i / 48, cc = i % 48;
        int idx = (t0 + tt) * 64 + cc;
        float s = 0.f;
        #pragma unroll
        for (int p = 0; p < KSX; ++p) s += part[idx + p * S];
        if (cc < 32) sdt[tt][cc] = s; else bsm[tt][cc - 32] = s;
    }
    bf16x8 wd[4];
    #pragma unroll
    for (int p = 0; p < 4; ++p) wd[p] = *(const bf16x8*)(wdt + (size_t)d * 32 + p * 8);
    float bd = dtb[d];
    float A2[16];
    {
        float a[16];
        #pragma unroll
        for (int q = 0; q < 4; ++q)
            *(float4*)(a + q * 4) = ((const float4*)(A_log + (size_t)d * 16))[q];
        #pragma unroll
        for (int n = 0; n < 16; ++n)
            A2[n] = -__expf(a[n]) * 1.44269504f;   // A * log2(e)
    }
    float h[16], ap[16];
    #pragma unroll
    for (int n = 0; n < 16; ++n) { h[n] = 0.f; ap[n] = 1.f; }
    __syncthreads();
    for (int tt = 0; tt < LC; ++tt) {
        int t = t0 + tt;
        float dtv = bd;
        #pragma unroll
        for (int p = 0; p < 4; ++p)
            #pragma unroll
            for (int e = 0; e < 8; ++e)
                dtv = fmaf(sdt[tt][p * 8 + e], bf2f((ushort)wd[p][e]), dtv);
        ushort dbf = f2bf(act_softplus(dtv));
        delta_bf[(size_t)t * DI + d] = dbf;
        float dt_ = bf2f(dbf);
        float du = dt_ * bf2f(u[(size_t)t * DI + d]);
        #pragma unroll
        for (int n = 0; n < 16; ++n) {
            float dA = exp2f(dt_ * A2[n]);
            h[n] = fmaf(dA, h[n], du * bsm[tt][n]);
            ap[n] *= dA;
        }
    }
    size_t base = ((size_t)c * DI + d) * 16;
    #pragma unroll
    for (int q = 0; q < 4; ++q) {
        ((float4*)(hend + base))[q]  = *(float4*)(h + q * 4);
        ((float4*)(aprod + base))[q] = *(float4*)(ap + q * 4);
    }
}

// Phase B: serial over chunks, j-in-lanes coalesced, float4 per thread, unroll-8.
__global__ __launch_bounds__(64) void chunk_prefix_kernel(
    const float* __restrict__ hend, float* __restrict__ aprod_hin)
{
    int j4 = (blockIdx.x * 64 + threadIdx.x) * 4;   // over DI*16 = 16384
    float4 h = { 0.f, 0.f, 0.f, 0.f };
    for (int cg = 0; cg < CH; cg += 8) {
        float4 ap[8], he[8];
        #pragma unroll
        for (int q = 0; q < 8; ++q) {
            size_t o = (size_t)(cg + q) * (DI * Nst) + j4;
            ap[q] = *(const float4*)(aprod_hin + o);
            he[q] = *(const float4*)(hend + o);
        }
        #pragma unroll
        for (int q = 0; q < 8; ++q) {
            size_t o = (size_t)(cg + q) * (DI * Nst) + j4;
            *(float4*)(aprod_hin + o) = h;
            h.x = fmaf(ap[q].x, h.x, he[q].x);
            h.y = fmaf(ap[q].y, h.y, he[q].y);
            h.z = fmaf(ap[q].z, h.z, he[q].z);
            h.w = fmaf(ap[q].w, h.w, he[q].w);
        }
    }
}

// Phase C: stages B,C sums from partials; reads delta_bf written by phase A.
__global__ __launch_bounds__(256) void scan_apply_kernel(
    const float* __restrict__ part, const ushort* __restrict__ delta,
    const ushort* __restrict__ u, const float* __restrict__ A_log,
    const float* __restrict__ Dp, const ushort* __restrict__ xz,
    const float* __restrict__ hin, ushort* __restrict__ y)
{
    __shared__ float bsm[LC][16], csm[LC][16];
    int tid = threadIdx.x;
    int c = blockIdx.x;
    int d = blockIdx.y * 256 + tid;
    int t0 = c * LC;
    const int S = L_SEQ * 64;
    for (int i = tid; i < LC * 32; i += 256) {
        int tt = i >> 5, k = i & 31;
        int idx = (t0 + tt) * 64 + 32 + k;
        float s = 0.f;
        #pragma unroll
        for (int p = 0; p < KSX; ++p) s += part[idx + p * S];
        if (k < 16) bsm[tt][k] = s; else csm[tt][k - 16] = s;
    }
    float A2[16];
    {
        float a[16];
        #pragma unroll
        for (int q = 0; q < 4; ++q)
            *(float4*)(a + q * 4) = ((const float4*)(A_log + (size_t)d * 16))[q];
        #pragma unroll
        for (int n = 0; n < 16; ++n)
            A2[n] = -__expf(a[n]) * 1.44269504f;
    }
    float h[16];
    size_t base = ((size_t)c * DI + d) * 16;
    #pragma unroll
    for (int q = 0; q < 4; ++q)
        *(float4*)(h + q * 4) = ((const float4*)(hin + base))[q];
    float Dval = Dp[d];
    __syncthreads();
    for (int tt = 0; tt < LC; ++tt) {
        int t = t0 + tt;
        float dt_ = bf2f(delta[(size_t)t * DI + d]);
        float u_  = bf2f(u[(size_t)t * DI + d]);
        float du  = dt_ * u_;
        float acc = 0.f;
        #pragma unroll
        for (int n = 0; n < 16; ++n) {
            float dA = exp2f(dt_ * A2[n]);
            h[n] = fmaf(dA, h[n], du * bsm[tt][n]);
            acc = fmaf(h[n], csm[tt][n], acc);
        }
        float zv = bf2f(xz[(size_t)t * (2 * DI) + DI + d]);
        y[(size_t)t * DI + d] = f2bf((acc + u_ * Dval) * silu_(zv));
    }
}

extern "C" void kernel_launch(void* const* d_in, const int* in_sizes, int n_in,
                              void* d_out, int out_size, void* d_ws, size_t ws_size,
                              hipStream_t stream)
{
    const float* hidden     = (const float*)d_in[0];
    const float* ln1_w      = (const float*)d_in[1];
    const float* ln1_b      = (const float*)d_in[2];
    const float* in_proj_w  = (const float*)d_in[3];
    const float* conv_w     = (const float*)d_in[4];
    const float* conv_b     = (const float*)d_in[5];
    const float* x_proj_w   = (const float*)d_in[6];
    const float* dt_proj_w  = (const float*)d_in[7];
    const float* dt_proj_b  = (const float*)d_in[8];
    const float* A_log      = (const float*)d_in[9];
    const float* D_param    = (const float*)d_in[10];
    const float* out_proj_w = (const float*)d_in[11];
    const float* block_norm_w = (const float*)d_in[12];
    const float* norm_f_w   = (const float*)d_in[13];
    const float* ln2_w      = (const float*)d_in[14];
    const float* ln2_b      = (const float*)d_in[15];
    const float* fc1_w      = (const float*)d_in[16];
    const float* fc1_b      = (const float*)d_in[17];
    const float* fc2_w      = (const float*)d_in[18];
    const float* fc2_b      = (const float*)d_in[19];

    char* P = (char*)d_ws;
    auto alloc = [&](size_t bytes) { char* r = P; P += (bytes + 255) & ~(size_t)255; return r; };
    float* hout   = (float*)alloc((size_t)L_SEQ * Dm * 4);
    float* res    = (float*)alloc((size_t)L_SEQ * Dm * 4);
    float* part   = (float*)alloc((size_t)KSX * L_SEQ * 64 * 4);    // x_proj split-K partials
    float* hend   = (float*)alloc((size_t)CH * DI * Nst * 4);       // 8MB
    float* aprod  = (float*)alloc((size_t)CH * DI * Nst * 4);       // 8MB; becomes hin in place
    ushort* h_bf  = (ushort*)alloc((size_t)L_SEQ * Dm * 2);
    ushort* delta_bf = (ushort*)alloc((size_t)L_SEQ * DI * 2);
    ushort* hn_bf = (ushort*)alloc((size_t)L_SEQ * Dm * 2);
    ushort* xz_bf = (ushort*)alloc((size_t)L_SEQ * 2 * DI * 2);
    ushort* xc_bf = (ushort*)alloc((size_t)L_SEQ * DI * 2);
    ushort* yb_bf = (ushort*)alloc((size_t)L_SEQ * DI * 2);
    ushort* w_in  = (ushort*)alloc((size_t)NL * 2 * DI * Dm * 2);
    ushort* w_out = (ushort*)alloc((size_t)NL * Dm * DI * 2);
    ushort* w_x   = (ushort*)alloc((size_t)NL * 64 * DI * 2);
    ushort* w_dt  = (ushort*)alloc((size_t)NL * DI * Rr * 2);
    ushort* w_fc1 = (ushort*)alloc((size_t)(4 * Dm) * Dm * 2);
    ushort* w_fc2 = (ushort*)alloc((size_t)Dm * (4 * Dm) * 2);
    float* out  = (float*)d_out;

    // setup: all weight casts + fused LN1/RMS0 in one launch
    {
        int n0 = NL * 2 * DI * Dm / 4, n1 = NL * Dm * DI / 4, n2 = NL * 64 * DI / 4;
        int n3 = NL * DI * Rr / 4, n4_ = 4 * Dm * Dm / 4, n5 = Dm * 4 * Dm / 4;
        int tot = n0 + n1 + n2 + n3 + n4_ + n5;
        int grid = 512 + (tot + 255) / 256;
        setup_kernel<<<grid, 256, 0, stream>>>(
            in_proj_w, w_in, n0, out_proj_w, w_out, n1, x_proj_w, w_x, n2,
            dt_proj_w, w_dt, n3, fc1_w, w_fc1, n4_, fc2_w, w_fc2, n5,
            hidden, ln1_w, ln1_b, block_norm_w, res, hn_bf);
    }

    dim3 gscan(CH, DI / 256);   // 128 x 4 = 512 blocks
    for (int i = 0; i < NL; ++i) {
        if (i) add_rms_kernel<<<L_SEQ / 4, 256, 0, stream>>>(h_bf, res,
                                                  block_norm_w + i * Dm, hn_bf);
        // in_proj: M=2048 N=2048 K=512 -> bf16 xz  (128x64 tile, 512 blocks = 2/CU)
        gemm_mfma<128, 64, 128, 1><<<dim3(2 * DI / 64, L_SEQ / 128), 256, 0, stream>>>(
            hn_bf, Dm, w_in + (size_t)i * 2 * DI * Dm, Dm, xz_bf, 2 * DI, nullptr, nullptr);
        // fused conv+silu + x_proj split-K=8 -> xc (bf16) + fp32 partials (256 blocks)
        xproj_conv_kernel<<<dim3(1, L_SEQ / 64, KSX), 256, 0, stream>>>(
            xz_bf, conv_w + i * DI * Kc, conv_b + i * DI,
            w_x + (size_t)i * 64 * DI, xc_bf, part);
        // 3-phase chunked scan (phase A finishes x_proj reduce + dt_proj)
        scan_chunk_kernel<<<gscan, 256, 0, stream>>>(part, xc_bf,
                                        w_dt + (size_t)i * DI * Rr, dt_proj_b + i * DI,
                                        A_log + (size_t)i * DI * Nst, hend, aprod, delta_bf);
        chunk_prefix_kernel<<<(DI * Nst) / 256, 64, 0, stream>>>(hend, aprod);
        scan_apply_kernel<<<gscan, 256, 0, stream>>>(part, delta_bf, xc_bf,
                                        A_log + (size_t)i * DI * Nst,
                                        D_param + i * DI, xz_bf, aprod, yb_bf);
        // out_proj: M=2048 N=512 K=1024 -> bf16 h  (64x32 tile, 512 blocks = 2/CU)
        gemm_mfma<64, 32, 128, 1><<<dim3(Dm / 32, L_SEQ / 64), 256, 0, stream>>>(
            yb_bf, DI, w_out + (size_t)i * Dm * DI, DI, h_bf, Dm, nullptr, nullptr);
    }

    final_ln2_kernel<<<L_SEQ / 4, 256, 0, stream>>>(h_bf, res, hidden, norm_f_w,
                                                ln2_w, ln2_b, hout, hn_bf);
    // fc1: M=2048 N=2048 K=512, bias+gelu -> bf16  (128x64 tile)
    gemm_mfma<128, 64, 128, 2><<<dim3(2048 / 64, L_SEQ / 128), 256, 0, stream>>>(
        hn_bf, Dm, w_fc1, Dm, xz_bf, 2048, fc1_b, nullptr);
    // fc2: M=2048 N=512 K=2048, bias+add(hout) -> fp32 out  (64x32 tile)
    gemm_mfma<64, 32, 128, 4><<<dim3(Dm / 32, L_SEQ / 64), 256, 0, stream>>>(
        xz_bf, 2048, w_fc2, 2048, out, Dm, fc2_b, hout);
}

// Round 18
// 390.427 us; speedup vs baseline: 1.2285x; 1.0318x over previous
//
#include <hip/hip_runtime.h>
#include <hip/hip_bf16.h>
#include <math.h>

#define L_SEQ 2048
#define Dm    512
#define DI    1024
#define Nst   16
#define Kc    4
#define Rr    32
#define NL    4
#define CH    128
#define LC    (L_SEQ / CH)   // 16
#define KSX   8              // x_proj split-K

typedef __attribute__((ext_vector_type(8))) short bf16x8;
typedef __attribute__((ext_vector_type(4))) float f32x4;

// ---------------- helpers ----------------
__device__ __forceinline__ float act_softplus(float x) {
    return fmaxf(x, 0.f) + log1pf(__expf(-fabsf(x)));
}
__device__ __forceinline__ float act_gelu(float x) {
    float c = 0.7978845608028654f * (x + 0.044715f * x * x * x);
    float t = 1.f - 2.f / (__expf(2.f * c) + 1.f);   // tanh(c)
    return 0.5f * x * (1.f + t);
}
__device__ __forceinline__ float silu_(float x) {
    return x / (1.f + __expf(-x));
}
__device__ __forceinline__ ushort f2bf(float f) {
    union { float f; unsigned u; } c; c.f = f;
    unsigned r = c.u + 0x7fffu + ((c.u >> 16) & 1u);
    return (ushort)(r >> 16);
}
__device__ __forceinline__ float bf2f(ushort u) {
    union { unsigned u; float f; } c; c.u = ((unsigned)u) << 16;
    return c.f;
}
__device__ __forceinline__ float wave_sum(float v) {
    #pragma unroll
    for (int off = 32; off; off >>= 1) v += __shfl_xor(v, off);
    return v;
}

// ---------------- setup: all weight casts + fused LN1/RMS0 (one kernel) ----------------
__global__ __launch_bounds__(256) void setup_kernel(
    const float* __restrict__ s0, ushort* __restrict__ d0, int n0,
    const float* __restrict__ s1, ushort* __restrict__ d1, int n1,
    const float* __restrict__ s2, ushort* __restrict__ d2, int n2,
    const float* __restrict__ s3, ushort* __restrict__ d3, int n3,
    const float* __restrict__ s4, ushort* __restrict__ d4, int n4_,
    const float* __restrict__ s5, ushort* __restrict__ d5, int n5,
    const float* __restrict__ x, const float* __restrict__ w,
    const float* __restrict__ b, const float* __restrict__ rw,
    float* __restrict__ res, ushort* __restrict__ hn_bf)
{
    if (blockIdx.x < 512) {
        int lane = threadIdx.x & 63, wv = threadIdx.x >> 6;
        int row = blockIdx.x * 4 + wv;
        size_t base = (size_t)row * Dm + lane * 8;
        float v[8];
        *(float4*)(v)     = *(const float4*)(x + base);
        *(float4*)(v + 4) = *(const float4*)(x + base + 4);
        float s = 0.f, ss = 0.f;
        #pragma unroll
        for (int q = 0; q < 8; ++q) { s += v[q]; ss += v[q] * v[q]; }
        s = wave_sum(s); ss = wave_sum(ss);
        float mu = s * (1.f / Dm);
        float rs = rsqrtf(ss * (1.f / Dm) - mu * mu + 1e-5f);
        float wv8[8], bv8[8], rv8[8];
        *(float4*)(wv8)     = *(const float4*)(w + lane * 8);
        *(float4*)(wv8 + 4) = *(const float4*)(w + lane * 8 + 4);
        *(float4*)(bv8)     = *(const float4*)(b + lane * 8);
        *(float4*)(bv8 + 4) = *(const float4*)(b + lane * 8 + 4);
        *(float4*)(rv8)     = *(const float4*)(rw + lane * 8);
        *(float4*)(rv8 + 4) = *(const float4*)(rw + lane * 8 + 4);
        float o[8], ss2 = 0.f;
        #pragma unroll
        for (int q = 0; q < 8; ++q) {
            o[q] = (v[q] - mu) * rs * wv8[q] + bv8[q];
            ss2 += o[q] * o[q];
        }
        *(float4*)(res + base)     = *(float4*)(o);
        *(float4*)(res + base + 4) = *(float4*)(o + 4);
        ss2 = wave_sum(ss2);
        float rr = rsqrtf(ss2 * (1.f / Dm) + 1e-5f);
        bf16x8 hb;
        #pragma unroll
        for (int q = 0; q < 8; ++q) hb[q] = (short)f2bf(o[q] * rr * rv8[q]);
        *(bf16x8*)(hn_bf + base) = hb;
        return;
    }
    int i = (blockIdx.x - 512) * 256 + threadIdx.x;
    const float* s; ushort* d;
    if (i < n0) { s = s0; d = d0; }
    else { i -= n0; if (i < n1) { s = s1; d = d1; }
    else { i -= n1; if (i < n2) { s = s2; d = d2; }
    else { i -= n2; if (i < n3) { s = s3; d = d3; }
    else { i -= n3; if (i < n4_) { s = s4; d = d4; }
    else { i -= n4_; if (i < n5) { s = s5; d = d5; } else return; } } } } }
    float4 v = ((const float4*)s)[i];
    ushort4 o;
    o.x = f2bf(v.x); o.y = f2bf(v.y); o.z = f2bf(v.z); o.w = f2bf(v.w);
    ((ushort4*)d)[i] = o;
}

// ---------------- residual add + RMSNorm: res += h(bf16); hn = RMS(res)*w ----------------
__global__ __launch_bounds__(256) void add_rms_kernel(const ushort* __restrict__ hb,
    float* __restrict__ res, const float* __restrict__ w, ushort* __restrict__ rms_out)
{
    int lane = threadIdx.x & 63, wv = threadIdx.x >> 6;
    int row = blockIdx.x * 4 + wv;
    size_t base = (size_t)row * Dm + lane * 8;
    bf16x8 hv = *(const bf16x8*)(hb + base);
    float v[8];
    *(float4*)(v)     = *(const float4*)(res + base);
    *(float4*)(v + 4) = *(const float4*)(res + base + 4);
    float ss = 0.f;
    #pragma unroll
    for (int q = 0; q < 8; ++q) {
        v[q] += bf2f((ushort)hv[q]);
        ss += v[q] * v[q];
    }
    *(float4*)(res + base)     = *(float4*)(v);
    *(float4*)(res + base + 4) = *(float4*)(v + 4);
    ss = wave_sum(ss);
    float rr = rsqrtf(ss * (1.f / Dm) + 1e-5f);
    float wv8[8];
    *(float4*)(wv8)     = *(const float4*)(w + lane * 8);
    *(float4*)(wv8 + 4) = *(const float4*)(w + lane * 8 + 4);
    bf16x8 ob;
    #pragma unroll
    for (int q = 0; q < 8; ++q) ob[q] = (short)f2bf(v[q] * rr * wv8[q]);
    *(bf16x8*)(rms_out + base) = ob;
}

// ---------------- fused: hout = shortcut + RMS(h+res)*wf; hn = LN(hout)*w2+b2 ----------------
__global__ __launch_bounds__(256) void final_ln2_kernel(const ushort* __restrict__ hb,
    const float* __restrict__ res, const float* __restrict__ shortcut,
    const float* __restrict__ wf, const float* __restrict__ w2,
    const float* __restrict__ b2, float* __restrict__ hout,
    ushort* __restrict__ yb16)
{
    int lane = threadIdx.x & 63, wv = threadIdx.x >> 6;
    int row = blockIdx.x * 4 + wv;
    size_t base = (size_t)row * Dm + lane * 8;
    bf16x8 hv = *(const bf16x8*)(hb + base);
    float v[8];
    *(float4*)(v)     = *(const float4*)(res + base);
    *(float4*)(v + 4) = *(const float4*)(res + base + 4);
    float ss = 0.f;
    #pragma unroll
    for (int q = 0; q < 8; ++q) {
        v[q] += bf2f((ushort)hv[q]);
        ss += v[q] * v[q];
    }
    ss = wave_sum(ss);
    float rs = rsqrtf(ss * (1.f / Dm) + 1e-5f);
    float sc[8], wf8[8];
    *(float4*)(sc)     = *(const float4*)(shortcut + base);
    *(float4*)(sc + 4) = *(const float4*)(shortcut + base + 4);
    *(float4*)(wf8)     = *(const float4*)(wf + lane * 8);
    *(float4*)(wf8 + 4) = *(const float4*)(wf + lane * 8 + 4);
    float t[8], s2 = 0.f, ss2 = 0.f;
    #pragma unroll
    for (int q = 0; q < 8; ++q) {
        t[q] = sc[q] + v[q] * rs * wf8[q];
        s2 += t[q]; ss2 += t[q] * t[q];
    }
    *(float4*)(hout + base)     = *(float4*)(t);
    *(float4*)(hout + base + 4) = *(float4*)(t + 4);
    s2 = wave_sum(s2); ss2 = wave_sum(ss2);
    float mu = s2 * (1.f / Dm);
    float rsig = rsqrtf(ss2 * (1.f / Dm) - mu * mu + 1e-5f);
    float w28[8], b28[8];
    *(float4*)(w28)     = *(const float4*)(w2 + lane * 8);
    *(float4*)(w28 + 4) = *(const float4*)(w2 + lane * 8 + 4);
    *(float4*)(b28)     = *(const float4*)(b2 + lane * 8);
    *(float4*)(b28 + 4) = *(const float4*)(b2 + lane * 8 + 4);
    bf16x8 ob;
    #pragma unroll
    for (int q = 0; q < 8; ++q) ob[q] = (short)f2bf((t[q] - mu) * rsig * w28[q] + b28[q]);
    *(bf16x8*)(yb16 + base) = ob;
}

// ---------------- MFMA bf16 GEMM: C(M,N) = A(M,K) * W(N,K)^T ----------------
// EPI: 1 = bf16 store; 2 = bias+gelu -> bf16; 4 = bias+addsrc -> f32
template<int BM, int BN, int BK, int EPI>
__global__ __launch_bounds__(256) void gemm_mfma(
    const ushort* __restrict__ A, int lda,
    const ushort* __restrict__ W, int K,
    void* __restrict__ Cout, int ldc,
    const float* __restrict__ bias, const float* __restrict__ addsrc)
{
    constexpr int ROWB  = BK * 2;
    constexpr int SMASK = (ROWB / 16) - 1;
    constexpr int KK    = BK / 32;
    constexpr int WM = BM / 2, WN = BN / 2;
    constexpr int FM = WM / 16, FN = WN / 16;
    constexpr int ISS_A = (BM * ROWB) / 4096;
    constexpr int ISS_W = (BN * ROWB) / 4096;

    __shared__ __align__(16) ushort As[BM * BK];
    __shared__ __align__(16) ushort Ws[BN * BK];

    int tid = threadIdx.x;
    int wave = tid >> 6, lane = tid & 63;
    int wr = wave >> 1, wc = wave & 1;
    int l16 = lane & 15, lk = lane >> 4;
    int bm = blockIdx.y * BM, bn = blockIdx.x * BN;

    const ushort* srcA[ISS_A];
    const ushort* srcW[ISS_W];
    #pragma unroll
    for (int s = 0; s < ISS_A; ++s) {
        int off = s * 4096 + wave * 1024 + lane * 16;
        int row = off / ROWB;
        int slot = (off % ROWB) >> 4;
        int col = ((slot ^ (row & SMASK)) << 3);
        srcA[s] = A + (size_t)(bm + row) * lda + col;
    }
    #pragma unroll
    for (int s = 0; s < ISS_W; ++s) {
        int off = s * 4096 + wave * 1024 + lane * 16;
        int row = off / ROWB;
        int slot = (off % ROWB) >> 4;
        int col = ((slot ^ (row & SMASK)) << 3);
        srcW[s] = W + (size_t)(bn + row) * K + col;
    }
    int aoff[FM][KK], woff[FN][KK];
    #pragma unroll
    for (int i = 0; i < FM; ++i) {
        int row = wr * WM + i * 16 + l16;
        #pragma unroll
        for (int kk = 0; kk < KK; ++kk)
            aoff[i][kk] = row * BK + ((((kk << 2) | lk) ^ (row & SMASK)) << 3);
    }
    #pragma unroll
    for (int j = 0; j < FN; ++j) {
        int row = wc * WN + j * 16 + l16;
        #pragma unroll
        for (int kk = 0; kk < KK; ++kk)
            woff[j][kk] = row * BK + ((((kk << 2) | lk) ^ (row & SMASK)) << 3);
    }

    f32x4 acc[FM][FN] = {};

    for (int k0 = 0; k0 < K; k0 += BK) {
        #pragma unroll
        for (int s = 0; s < ISS_A; ++s)
            __builtin_amdgcn_global_load_lds(
                (const __attribute__((address_space(1))) void*)(srcA[s] + k0),
                (__attribute__((address_space(3))) void*)((char*)As + s * 4096 + wave * 1024),
                16, 0, 0);
        #pragma unroll
        for (int s = 0; s < ISS_W; ++s)
            __builtin_amdgcn_global_load_lds(
                (const __attribute__((address_space(1))) void*)(srcW[s] + k0),
                (__attribute__((address_space(3))) void*)((char*)Ws + s * 4096 + wave * 1024),
                16, 0, 0);
        __syncthreads();
        #pragma unroll
        for (int kk = 0; kk < KK; ++kk) {
            bf16x8 af[FM], wf[FN];
            #pragma unroll
            for (int i = 0; i < FM; ++i) af[i] = *(const bf16x8*)(As + aoff[i][kk]);
            #pragma unroll
            for (int j = 0; j < FN; ++j) wf[j] = *(const bf16x8*)(Ws + woff[j][kk]);
            #pragma unroll
            for (int i = 0; i < FM; ++i)
                #pragma unroll
                for (int j = 0; j < FN; ++j)
                    acc[i][j] = __builtin_amdgcn_mfma_f32_16x16x32_bf16(af[i], wf[j], acc[i][j], 0, 0, 0);
        }
        __syncthreads();
    }

    int orow0 = bm + wr * WM, ocol0 = bn + wc * WN;
    #pragma unroll
    for (int j = 0; j < FN; ++j) {
        int col = ocol0 + j * 16 + l16;
        float bj = 0.f;
        if constexpr (EPI == 2 || EPI == 4) bj = bias[col];
        #pragma unroll
        for (int i = 0; i < FM; ++i) {
            #pragma unroll
            for (int r = 0; r < 4; ++r) {
                int row = orow0 + i * 16 + lk * 4 + r;
                float v = acc[i][j][r];
                if constexpr (EPI == 1) {
                    ((ushort*)Cout)[(size_t)row * ldc + col] = f2bf(v);
                } else if constexpr (EPI == 2) {
                    ((ushort*)Cout)[(size_t)row * ldc + col] = f2bf(act_gelu(v + bj));
                } else if constexpr (EPI == 4) {
                    ((float*)Cout)[(size_t)row * ldc + col] = v + bj + addsrc[(size_t)row * ldc + col];
                }
            }
        }
    }
}

// ---------------- fused conv+silu + x_proj GEMM (split-K=8 over d; 256 blocks) ----------------
__global__ __launch_bounds__(256) void xproj_conv_kernel(
    const ushort* __restrict__ xz, const float* __restrict__ cw,
    const float* __restrict__ cb, const ushort* __restrict__ W,
    ushort* __restrict__ xc, float* __restrict__ part)
{
    constexpr int BM = 64, BN = 64, BK = 64;
    constexpr int ROWB  = BK * 2;            // 128
    constexpr int SMASK = (ROWB / 16) - 1;   // 7
    constexpr int KK    = BK / 32;           // 2
    constexpr int WM = 32, WN = 32, FM = 2, FN = 2;

    __shared__ __align__(16) ushort As[BM * BK];
    __shared__ __align__(16) ushort Ws[BN * BK];

    int tid = threadIdx.x;
    int wave = tid >> 6, lane = tid & 63;
    int wr = wave >> 1, wc = wave & 1;
    int l16 = lane & 15, lk = lane >> 4;
    int bm = blockIdx.y * BM;
    int z = blockIdx.z;
    int kbeg = z * (DI / KSX);               // 128 per split

    const ushort* srcW[2];
    #pragma unroll
    for (int s = 0; s < 2; ++s) {
        int off = s * 4096 + wave * 1024 + lane * 16;
        int row = off / ROWB;
        int slot = (off % ROWB) >> 4;
        int col = ((slot ^ (row & SMASK)) << 3);
        srcW[s] = W + (size_t)row * DI + kbeg + col;
    }
    int aoff[FM][KK], woff[FN][KK];
    #pragma unroll
    for (int i = 0; i < FM; ++i) {
        int row = wr * WM + i * 16 + l16;
        #pragma unroll
        for (int kk = 0; kk < KK; ++kk)
            aoff[i][kk] = row * BK + ((((kk << 2) | lk) ^ (row & SMASK)) << 3);
    }
    #pragma unroll
    for (int j = 0; j < FN; ++j) {
        int row = wc * WN + j * 16 + l16;
        #pragma unroll
        for (int kk = 0; kk < KK; ++kk)
            woff[j][kk] = row * BK + ((((kk << 2) | lk) ^ (row & SMASK)) << 3);
    }

    f32x4 acc[FM][FN] = {};

    for (int k0 = 0; k0 < DI / KSX; k0 += BK) {
        #pragma unroll
        for (int s = 0; s < 2; ++s)
            __builtin_amdgcn_global_load_lds(
                (const __attribute__((address_space(1))) void*)(srcW[s] + k0),
                (__attribute__((address_space(3))) void*)((char*)Ws + s * 4096 + wave * 1024),
                16, 0, 0);
        #pragma unroll
        for (int s = 0; s < 2; ++s) {
            int off = s * 4096 + wave * 1024 + lane * 16;
            int row = off >> 7;              // /128
            int slot = (off >> 4) & 7;
            int t = bm + row;
            int dcol = kbeg + k0 + slot * 8;
            float a[8];
            float4 c4[8];
            #pragma unroll
            for (int q = 0; q < 8; ++q) {
                a[q] = cb[dcol + q];
                c4[q] = *(const float4*)(cw + (size_t)(dcol + q) * 4);
            }
            #pragma unroll
            for (int k = 0; k < 4; ++k) {
                int tt = t + k - 3;
                if (tt >= 0) {
                    bf16x8 xv = *(const bf16x8*)(xz + (size_t)tt * (2 * DI) + dcol);
                    #pragma unroll
                    for (int q = 0; q < 8; ++q) {
                        float wk = (k == 0) ? c4[q].x : (k == 1) ? c4[q].y
                                 : (k == 2) ? c4[q].z : c4[q].w;
                        a[q] = fmaf(wk, bf2f((ushort)xv[q]), a[q]);
                    }
                }
            }
            bf16x8 o;
            #pragma unroll
            for (int q = 0; q < 8; ++q) o[q] = (short)f2bf(silu_(a[q]));
            *(bf16x8*)(xc + (size_t)t * DI + dcol) = o;
            *(bf16x8*)(As + row * BK + ((slot ^ (row & SMASK)) << 3)) = o;
        }
        __syncthreads();
        #pragma unroll
        for (int kk = 0; kk < KK; ++kk) {
            bf16x8 af[FM], wf[FN];
            #pragma unroll
            for (int i = 0; i < FM; ++i) af[i] = *(const bf16x8*)(As + aoff[i][kk]);
            #pragma unroll
            for (int j = 0; j < FN; ++j) wf[j] = *(const bf16x8*)(Ws + woff[j][kk]);
            #pragma unroll
            for (int i = 0; i < FM; ++i)
                #pragma unroll
                for (int j = 0; j < FN; ++j)
                    acc[i][j] = __builtin_amdgcn_mfma_f32_16x16x32_bf16(af[i], wf[j], acc[i][j], 0, 0, 0);
        }
        __syncthreads();
    }

    float* coutf = part + (size_t)z * L_SEQ * 64;
    int orow0 = bm + wr * WM, ocol0 = wc * WN;
    #pragma unroll
    for (int j = 0; j < FN; ++j) {
        int col = ocol0 + j * 16 + l16;
        #pragma unroll
        for (int i = 0; i < FM; ++i)
            #pragma unroll
            for (int r = 0; r < 4; ++r) {
                int row = orow0 + i * 16 + lk * 4 + r;
                coutf[(size_t)row * 64 + col] = acc[i][j][r];
            }
    }
}

// ---------------- 3-phase chunked SSM scan, 16 n-states per thread ----------------
__global__ __launch_bounds__(256) void scan_chunk_kernel(
    const float* __restrict__ part, const ushort* __restrict__ u,
    const ushort* __restrict__ wdt, const float* __restrict__ dtb,
    const float* __restrict__ A_log,
    float* __restrict__ hend, float* __restrict__ aprod,
    ushort* __restrict__ delta_bf)
{
    __shared__ float sdt[LC][32];
    __shared__ float bsm[LC][16];
    int tid = threadIdx.x;
    int c = blockIdx.x;
    int d = blockIdx.y * 256 + tid;
    int t0 = c * LC;
    const int S = L_SEQ * 64;
    for (int i = tid; i < LC * 48; i += 256) {
        int tt = i / 48, cc = i % 48;
        int idx = (t0 + tt) * 64 + cc;
        float s = 0.f;
        #pragma unroll
        for (int p = 0; p < KSX; ++p) s += part[idx + p * S];
        if (cc < 32) sdt[tt][cc] = s; else bsm[tt][cc - 32] = s;
    }
    bf16x8 wd[4];
    #pragma unroll
    for (int p = 0; p < 4; ++p) wd[p] = *(const bf16x8*)(wdt + (size_t)d * 32 + p * 8);
    float bd = dtb[d];
    float A2[16];
    {
        float a[16];
        #pragma unroll
        for (int q = 0; q < 4; ++q)
            *(float4*)(a + q * 4) = ((const float4*)(A_log + (size_t)d * 16))[q];
        #pragma unroll
        for (int n = 0; n < 16; ++n)
            A2[n] = -__expf(a[n]) * 1.44269504f;   // A * log2(e)
    }
    float h[16], ap[16];
    #pragma unroll
    for (int n = 0; n < 16; ++n) { h[n] = 0.f; ap[n] = 1.f; }
    __syncthreads();
    for (int tt = 0; tt < LC; ++tt) {
        int t = t0 + tt;
        float dtv = bd;
        #pragma unroll
        for (int p = 0; p < 4; ++p)
            #pragma unroll
            for (int e = 0; e < 8; ++e)
                dtv = fmaf(sdt[tt][p * 8 + e], bf2f((ushort)wd[p][e]), dtv);
        ushort dbf = f2bf(act_softplus(dtv));
        delta_bf[(size_t)t * DI + d] = dbf;
        float dt_ = bf2f(dbf);
        float du = dt_ * bf2f(u[(size_t)t * DI + d]);
        #pragma unroll
        for (int n = 0; n < 16; ++n) {
            float dA = exp2f(dt_ * A2[n]);
            h[n] = fmaf(dA, h[n], du * bsm[tt][n]);
            ap[n] *= dA;
        }
    }
    size_t base = ((size_t)c * DI + d) * 16;
    #pragma unroll
    for (int q = 0; q < 4; ++q) {
        ((float4*)(hend + base))[q]  = *(float4*)(h + q * 4);
        ((float4*)(aprod + base))[q] = *(float4*)(ap + q * 4);
    }
}

// Phase B: serial over chunks per (d,n), j-in-lanes (coalesced); unroll-8 for ILP.
__global__ __launch_bounds__(64) void chunk_prefix_kernel(
    const float* __restrict__ hend, float* __restrict__ aprod_hin)
{
    int j = blockIdx.x * 64 + threadIdx.x;   // over DI*16
    float h = 0.f;
    for (int cg = 0; cg < CH; cg += 8) {
        float ap[8], he[8];
        #pragma unroll
        for (int q = 0; q < 8; ++q) {
            size_t o = (size_t)(cg + q) * (DI * Nst) + j;
            ap[q] = aprod_hin[o]; he[q] = hend[o];
        }
        #pragma unroll
        for (int q = 0; q < 8; ++q) {
            size_t o = (size_t)(cg + q) * (DI * Nst) + j;
            aprod_hin[o] = h;                 // h_in for chunk cg+q
            h = fmaf(ap[q], h, he[q]);
        }
    }
}

// Phase C: stages B,C sums from partials; reads delta_bf written by phase A.
__global__ __launch_bounds__(256) void scan_apply_kernel(
    const float* __restrict__ part, const ushort* __restrict__ delta,
    const ushort* __restrict__ u, const float* __restrict__ A_log,
    const float* __restrict__ Dp, const ushort* __restrict__ xz,
    const float* __restrict__ hin, ushort* __restrict__ y)
{
    __shared__ float bsm[LC][16], csm[LC][16];
    int tid = threadIdx.x;
    int c = blockIdx.x;
    int d = blockIdx.y * 256 + tid;
    int t0 = c * LC;
    const int S = L_SEQ * 64;
    for (int i = tid; i < LC * 32; i += 256) {
        int tt = i >> 5, k = i & 31;
        int idx = (t0 + tt) * 64 + 32 + k;
        float s = 0.f;
        #pragma unroll
        for (int p = 0; p < KSX; ++p) s += part[idx + p * S];
        if (k < 16) bsm[tt][k] = s; else csm[tt][k - 16] = s;
    }
    float A2[16];
    {
        float a[16];
        #pragma unroll
        for (int q = 0; q < 4; ++q)
            *(float4*)(a + q * 4) = ((const float4*)(A_log + (size_t)d * 16))[q];
        #pragma unroll
        for (int n = 0; n < 16; ++n)
            A2[n] = -__expf(a[n]) * 1.44269504f;
    }
    float h[16];
    size_t base = ((size_t)c * DI + d) * 16;
    #pragma unroll
    for (int q = 0; q < 4; ++q)
        *(float4*)(h + q * 4) = ((const float4*)(hin + base))[q];
    float Dval = Dp[d];
    __syncthreads();
    for (int tt = 0; tt < LC; ++tt) {
        int t = t0 + tt;
        float dt_ = bf2f(delta[(size_t)t * DI + d]);
        float u_  = bf2f(u[(size_t)t * DI + d]);
        float du  = dt_ * u_;
        float acc = 0.f;
        #pragma unroll
        for (int n = 0; n < 16; ++n) {
            float dA = exp2f(dt_ * A2[n]);
            h[n] = fmaf(dA, h[n], du * bsm[tt][n]);
            acc = fmaf(h[n], csm[tt][n], acc);
        }
        float zv = bf2f(xz[(size_t)t * (2 * DI) + DI + d]);
        y[(size_t)t * DI + d] = f2bf((acc + u_ * Dval) * silu_(zv));
    }
}

extern "C" void kernel_launch(void* const* d_in, const int* in_sizes, int n_in,
                              void* d_out, int out_size, void* d_ws, size_t ws_size,
                              hipStream_t stream)
{
    const float* hidden     = (const float*)d_in[0];
    const float* ln1_w      = (const float*)d_in[1];
    const float* ln1_b      = (const float*)d_in[2];
    const float* in_proj_w  = (const float*)d_in[3];
    const float* conv_w     = (const float*)d_in[4];
    const float* conv_b     = (const float*)d_in[5];
    const float* x_proj_w   = (const float*)d_in[6];
    const float* dt_proj_w  = (const float*)d_in[7];
    const float* dt_proj_b  = (const float*)d_in[8];
    const float* A_log      = (const float*)d_in[9];
    const float* D_param    = (const float*)d_in[10];
    const float* out_proj_w = (const float*)d_in[11];
    const float* block_norm_w = (const float*)d_in[12];
    const float* norm_f_w   = (const float*)d_in[13];
    const float* ln2_w      = (const float*)d_in[14];
    const float* ln2_b      = (const float*)d_in[15];
    const float* fc1_w      = (const float*)d_in[16];
    const float* fc1_b      = (const float*)d_in[17];
    const float* fc2_w      = (const float*)d_in[18];
    const float* fc2_b      = (const float*)d_in[19];

    char* P = (char*)d_ws;
    auto alloc = [&](size_t bytes) { char* r = P; P += (bytes + 255) & ~(size_t)255; return r; };
    float* hout   = (float*)alloc((size_t)L_SEQ * Dm * 4);
    float* res    = (float*)alloc((size_t)L_SEQ * Dm * 4);
    float* part   = (float*)alloc((size_t)KSX * L_SEQ * 64 * 4);    // x_proj split-K partials
    float* hend   = (float*)alloc((size_t)CH * DI * Nst * 4);       // 8MB
    float* aprod  = (float*)alloc((size_t)CH * DI * Nst * 4);       // 8MB; becomes hin in place
    ushort* h_bf  = (ushort*)alloc((size_t)L_SEQ * Dm * 2);
    ushort* delta_bf = (ushort*)alloc((size_t)L_SEQ * DI * 2);
    ushort* hn_bf = (ushort*)alloc((size_t)L_SEQ * Dm * 2);
    ushort* xz_bf = (ushort*)alloc((size_t)L_SEQ * 2 * DI * 2);
    ushort* xc_bf = (ushort*)alloc((size_t)L_SEQ * DI * 2);
    ushort* yb_bf = (ushort*)alloc((size_t)L_SEQ * DI * 2);
    ushort* w_in  = (ushort*)alloc((size_t)NL * 2 * DI * Dm * 2);
    ushort* w_out = (ushort*)alloc((size_t)NL * Dm * DI * 2);
    ushort* w_x   = (ushort*)alloc((size_t)NL * 64 * DI * 2);
    ushort* w_dt  = (ushort*)alloc((size_t)NL * DI * Rr * 2);
    ushort* w_fc1 = (ushort*)alloc((size_t)(4 * Dm) * Dm * 2);
    ushort* w_fc2 = (ushort*)alloc((size_t)Dm * (4 * Dm) * 2);
    float* out  = (float*)d_out;

    // setup: all weight casts + fused LN1/RMS0 in one launch
    {
        int n0 = NL * 2 * DI * Dm / 4, n1 = NL * Dm * DI / 4, n2 = NL * 64 * DI / 4;
        int n3 = NL * DI * Rr / 4, n4_ = 4 * Dm * Dm / 4, n5 = Dm * 4 * Dm / 4;
        int tot = n0 + n1 + n2 + n3 + n4_ + n5;
        int grid = 512 + (tot + 255) / 256;
        setup_kernel<<<grid, 256, 0, stream>>>(
            in_proj_w, w_in, n0, out_proj_w, w_out, n1, x_proj_w, w_x, n2,
            dt_proj_w, w_dt, n3, fc1_w, w_fc1, n4_, fc2_w, w_fc2, n5,
            hidden, ln1_w, ln1_b, block_norm_w, res, hn_bf);
    }

    dim3 gscan(CH, DI / 256);   // 128 x 4 = 512 blocks
    for (int i = 0; i < NL; ++i) {
        if (i) add_rms_kernel<<<L_SEQ / 4, 256, 0, stream>>>(h_bf, res,
                                                  block_norm_w + i * Dm, hn_bf);
        // in_proj: M=2048 N=2048 K=512 -> bf16 xz  (128x64 tile, 512 blocks = 2/CU)
        gemm_mfma<128, 64, 128, 1><<<dim3(2 * DI / 64, L_SEQ / 128), 256, 0, stream>>>(
            hn_bf, Dm, w_in + (size_t)i * 2 * DI * Dm, Dm, xz_bf, 2 * DI, nullptr, nullptr);
        // fused conv+silu + x_proj split-K=8 -> xc (bf16) + fp32 partials (256 blocks)
        xproj_conv_kernel<<<dim3(1, L_SEQ / 64, KSX), 256, 0, stream>>>(
            xz_bf, conv_w + i * DI * Kc, conv_b + i * DI,
            w_x + (size_t)i * 64 * DI, xc_bf, part);
        // 3-phase chunked scan (phase A finishes x_proj reduce + dt_proj)
        scan_chunk_kernel<<<gscan, 256, 0, stream>>>(part, xc_bf,
                                        w_dt + (size_t)i * DI * Rr, dt_proj_b + i * DI,
                                        A_log + (size_t)i * DI * Nst, hend, aprod, delta_bf);
        chunk_prefix_kernel<<<(DI * Nst) / 64, 64, 0, stream>>>(hend, aprod);
        scan_apply_kernel<<<gscan, 256, 0, stream>>>(part, delta_bf, xc_bf,
                                        A_log + (size_t)i * DI * Nst,
                                        D_param + i * DI, xz_bf, aprod, yb_bf);
        // out_proj: M=2048 N=512 K=1024 -> bf16 h  (64x32 tile, 512 blocks = 2/CU)
        gemm_mfma<64, 32, 128, 1><<<dim3(Dm / 32, L_SEQ / 64), 256, 0, stream>>>(
            yb_bf, DI, w_out + (size_t)i * Dm * DI, DI, h_bf, Dm, nullptr, nullptr);
    }

    final_ln2_kernel<<<L_SEQ / 4, 256, 0, stream>>>(h_bf, res, hidden, norm_f_w,
                                                ln2_w, ln2_b, hout, hn_bf);
    // fc1: M=2048 N=2048 K=512, bias+gelu -> bf16  (128x64 tile)
    gemm_mfma<128, 64, 128, 2><<<dim3(2048 / 64, L_SEQ / 128), 256, 0, stream>>>(
        hn_bf, Dm, w_fc1, Dm, xz_bf, 2048, fc1_b, nullptr);
    // fc2: M=2048 N=512 K=2048, bias+add(hout) -> fp32 out  (64x32 tile)
    gemm_mfma<64, 32, 128, 4><<<dim3(Dm / 32, L_SEQ / 64), 256, 0, stream>>>(
        xz_bf, 2048, w_fc2, 2048, out, Dm, fc2_b, hout);
}